// Round 4
// baseline (23996.797 us; speedup 1.0000x reference)
//
#include <hip/hip_runtime.h>
#include <cstddef>

// ---------------------------------------------------------------------------
// VQ-VAE forward, f32, LDS-tiled convs with IC-blocked staging + register
// double-buffer prefetch (T14 async-stage). Batch-chunked to fit ws_size.
// Encoder stays f32: VQ argmin flips (bf16 noise) would exceed absmax.
// ---------------------------------------------------------------------------

// Conv2d k=4 s=2 p=1 (+ReLU). Block = 16x16 output tile, G output channels.
// Stages ICB input channels per round into LDS (34x34 halo, pitch 36 so the
// stride-2 float2 window reads are exact 2-way bank aliasing = free).
template<int CIN, int ICB, int G, int RELU>
__global__ __launch_bounds__(256) void conv_t(
    const float* __restrict__ in, const float* __restrict__ wt,
    const float* __restrict__ bias, float* __restrict__ out,
    int Cout, int Hin, int Win) {
  constexpr int NG = CIN / ICB;
  const int Hout = Hin >> 1, Wout = Win >> 1;
  const int TW = Wout >> 4;
  __shared__ float tile[ICB][34 * 36];
  const int tid = threadIdx.x;
  const int oxl = tid & 15, oyl = tid >> 4;
  const int tyt = blockIdx.x / TW, txt = blockIdx.x - tyt * TW;
  const int oy0 = tyt << 4, ox0 = txt << 4;
  const int cg = blockIdx.y % (Cout / G);
  const int b  = blockIdx.y / (Cout / G);
  const int co0 = cg * G;
  const int iy_org = 2 * oy0 - 1, ix_org = 2 * ox0 - 1;
  const float* ip = in + (size_t)b * CIN * Hin * Win;

  // staging slot coords (hoisted: 5 divisions once per thread)
  int soff[5], sdst[5]; bool sld[5], sst[5];
#pragma unroll
  for (int k = 0; k < 5; ++k) {
    int idx = tid + k * 256;
    int r = idx / 34, c = idx - r * 34;
    int iy = iy_org + r, ix = ix_org + c;
    sst[k] = idx < 34 * 34;
    sld[k] = sst[k] && (unsigned)iy < (unsigned)Hin && (unsigned)ix < (unsigned)Win;
    soff[k] = iy * Win + ix;
    sdst[k] = r * 36 + c;
  }

  float acc[G];
#pragma unroll
  for (int j = 0; j < G; ++j) acc[j] = bias[co0 + j];

  float pfA[ICB][5], pfB[ICB][5];
  auto loadg = [&](int g, float (&pf)[ICB][5]) {
#pragma unroll
    for (int c = 0; c < ICB; ++c) {
      const float* ic = ip + (size_t)(g * ICB + c) * Hin * Win;
#pragma unroll
      for (int k = 0; k < 5; ++k) pf[c][k] = sld[k] ? ic[soff[k]] : 0.0f;
    }
  };
  auto storeg = [&](float (&pf)[ICB][5]) {
#pragma unroll
    for (int c = 0; c < ICB; ++c)
#pragma unroll
      for (int k = 0; k < 5; ++k)
        if (sst[k]) tile[c][sdst[k]] = pf[c][k];
  };
  const int lb2 = oyl * 36 + oxl;     // float2 index of window origin
  auto computeg = [&](int g) {
#pragma unroll
    for (int c = 0; c < ICB; ++c) {
      const float2* t2 = (const float2*)&tile[c][0];
      float2 xv[8];
#pragma unroll
      for (int kh = 0; kh < 4; ++kh) {
        xv[kh * 2 + 0] = t2[lb2 + kh * 18 + 0];
        xv[kh * 2 + 1] = t2[lb2 + kh * 18 + 1];
      }
      const size_t wb = ((size_t)co0 * CIN + (size_t)(g * ICB + c)) * 16;
#pragma unroll
      for (int j = 0; j < G; ++j) {
        const float* wj = wt + wb + (size_t)j * CIN * 16;
#pragma unroll
        for (int kh = 0; kh < 4; ++kh) {
          float2 a = xv[kh * 2 + 0], b2 = xv[kh * 2 + 1];
          acc[j] = fmaf(a.x,  wj[kh * 4 + 0], acc[j]);
          acc[j] = fmaf(a.y,  wj[kh * 4 + 1], acc[j]);
          acc[j] = fmaf(b2.x, wj[kh * 4 + 2], acc[j]);
          acc[j] = fmaf(b2.y, wj[kh * 4 + 3], acc[j]);
        }
      }
    }
  };

  loadg(0, pfA);
  for (int g = 0; g < NG; g += 2) {
    __syncthreads();
    storeg(pfA);
    if (g + 1 < NG) loadg(g + 1, pfB);
    __syncthreads();
    computeg(g);
    if (g + 1 < NG) {
      __syncthreads();
      storeg(pfB);
      if (g + 2 < NG) loadg(g + 2, pfA);
      __syncthreads();
      computeg(g + 1);
    }
  }

  size_t cs = (size_t)Hout * Wout;
  float* op = out + ((size_t)(b * Cout + co0) * Hout + (oy0 + oyl)) * Wout + ox0 + oxl;
#pragma unroll
  for (int j = 0; j < G; ++j) {
    float v = acc[j];
    if (RELU) v = fmaxf(v, 0.0f);
    op[(size_t)j * cs] = v;
  }
}

// 1x1 conv (pre-VQ), no activation.
template<int CIN, int G>
__global__ __launch_bounds__(256) void conv1x1_k(
    const float* __restrict__ in, const float* __restrict__ wt,
    const float* __restrict__ bias, float* __restrict__ out,
    int Cout, int HW) {
  int hw = blockIdx.x * 256 + threadIdx.x;
  int cg = blockIdx.y % (Cout / G);
  int b  = blockIdx.y / (Cout / G);
  int co0 = cg * G;
  const float* ip = in + (size_t)b * CIN * HW + hw;
  float acc[G];
#pragma unroll
  for (int j = 0; j < G; ++j) acc[j] = bias[co0 + j];
#pragma unroll 4
  for (int ci = 0; ci < CIN; ++ci) {
    float xv = ip[(size_t)ci * HW];
#pragma unroll
    for (int j = 0; j < G; ++j)
      acc[j] = fmaf(xv, wt[(size_t)(co0 + j) * CIN + ci], acc[j]);
  }
  float* op = out + ((size_t)(b * Cout + co0)) * HW + hw;
#pragma unroll
  for (int j = 0; j < G; ++j) op[(size_t)j * HW] = acc[j];
}

// VQ nearest-neighbor: one thread per (b, n) vector of 64 dims.
__global__ __launch_bounds__(128) void vq_k(
    const float* __restrict__ ze, const float* __restrict__ emb,
    float* __restrict__ zq, float* __restrict__ partial) {
  __shared__ float4 se4[128 * 16];   // 32 KB
  __shared__ float red[128];
  int tid = threadIdx.x;
  int gid = blockIdx.x * 128 + tid;
  int b = gid >> 10, n = gid & 1023;
  const float* zp = ze + ((size_t)b << 16) + n;
  float4 v4[16];
#pragma unroll
  for (int d = 0; d < 16; ++d) {
    v4[d].x = zp[(size_t)(4 * d + 0) << 10];
    v4[d].y = zp[(size_t)(4 * d + 1) << 10];
    v4[d].z = zp[(size_t)(4 * d + 2) << 10];
    v4[d].w = zp[(size_t)(4 * d + 3) << 10];
  }
  float best = 1e30f; int bi = 0;
  for (int c = 0; c < 4; ++c) {
    __syncthreads();
    for (int i = tid; i < 2048; i += 128)
      se4[i] = ((const float4*)emb)[(c << 11) + i];
    __syncthreads();
    for (int k = 0; k < 128; ++k) {
      const float4* e = se4 + (k << 4);
      float s = 0.0f;
#pragma unroll
      for (int d = 0; d < 16; ++d) {
        float4 ev = e[d];
        float t0 = v4[d].x - ev.x; s = fmaf(t0, t0, s);
        float t1 = v4[d].y - ev.y; s = fmaf(t1, t1, s);
        float t2 = v4[d].z - ev.z; s = fmaf(t2, t2, s);
        float t3 = v4[d].w - ev.w; s = fmaf(t3, t3, s);
      }
      if (s < best) { best = s; bi = (c << 7) + k; }
    }
  }
  const float4* eb4 = (const float4*)emb + ((size_t)bi << 4);
  float* qp = zq + ((size_t)b << 16) + n;
  float ls = 0.0f;
#pragma unroll
  for (int d = 0; d < 16; ++d) {
    float4 q = eb4[d];
    qp[(size_t)(4 * d + 0) << 10] = q.x;
    qp[(size_t)(4 * d + 1) << 10] = q.y;
    qp[(size_t)(4 * d + 2) << 10] = q.z;
    qp[(size_t)(4 * d + 3) << 10] = q.w;
    float t0 = q.x - v4[d].x; ls = fmaf(t0, t0, ls);
    float t1 = q.y - v4[d].y; ls = fmaf(t1, t1, ls);
    float t2 = q.z - v4[d].z; ls = fmaf(t2, t2, ls);
    float t3 = q.w - v4[d].w; ls = fmaf(t3, t3, ls);
  }
  red[tid] = ls;
  __syncthreads();
  for (int s = 64; s > 0; s >>= 1) {
    if (tid < s) red[tid] += red[tid + s];
    __syncthreads();
  }
  if (tid == 0) partial[blockIdx.x] = red[0];
}

__global__ __launch_bounds__(256) void loss_fin(
    const float* __restrict__ partial, float* __restrict__ out) {
  __shared__ float red[256];
  int t = threadIdx.x;
  red[t] = partial[t];
  __syncthreads();
  for (int s = 128; s > 0; s >>= 1) {
    if (t < s) red[t] += red[t + s];
    __syncthreads();
  }
  if (t == 0) out[0] = red[0] * (2.0f / 2097152.0f);
}

// ConvTranspose2d k=4 s=2 p=1 (+ReLU/sigmoid). Block = 16x16 input positions,
// 2x2 outputs per thread, G channels. ICB channels staged per round
// (18x18 halo, pitch 24 -> exact 2-way bank aliasing on the b32 reads).
template<int CIN, int ICB, int G, int ACT>
__global__ __launch_bounds__(256) void convT_t(
    const float* __restrict__ in, const float* __restrict__ wt,
    const float* __restrict__ bias, float* __restrict__ out,
    int Cout, int Hin, int Win) {
  constexpr int NG = CIN / ICB;
  const int Hout = Hin * 2, Wout = Win * 2;
  const int TW = Win >> 4;
  __shared__ float tile[ICB][18 * 24];
  const int tid = threadIdx.x;
  const int txl = tid & 15, tyl = tid >> 4;
  const int tyt = blockIdx.x / TW, txt = blockIdx.x - tyt * TW;
  const int ty0 = tyt << 4, tx0 = txt << 4;
  const int og = blockIdx.y % (Cout / G);
  const int b  = blockIdx.y / (Cout / G);
  const int o0 = og * G;
  const int iy_org = ty0 - 1, ix_org = tx0 - 1;
  const float* ip = in + (size_t)b * CIN * Hin * Win;

  int soff[2], sdst[2]; bool sld[2], sst[2];
#pragma unroll
  for (int k = 0; k < 2; ++k) {
    int idx = tid + k * 256;
    int r = idx / 18, c = idx - r * 18;
    int iy = iy_org + r, ix = ix_org + c;
    sst[k] = idx < 18 * 18;
    sld[k] = sst[k] && (unsigned)iy < (unsigned)Hin && (unsigned)ix < (unsigned)Win;
    soff[k] = iy * Win + ix;
    sdst[k] = r * 24 + c;
  }

  float a00[G], a01[G], a10[G], a11[G];
#pragma unroll
  for (int j = 0; j < G; ++j) {
    float bb = bias[o0 + j];
    a00[j] = bb; a01[j] = bb; a10[j] = bb; a11[j] = bb;
  }

  float pfA[ICB][2], pfB[ICB][2];
  auto loadg = [&](int g, float (&pf)[ICB][2]) {
#pragma unroll
    for (int c = 0; c < ICB; ++c) {
      const float* ic = ip + (size_t)(g * ICB + c) * Hin * Win;
#pragma unroll
      for (int k = 0; k < 2; ++k) pf[c][k] = sld[k] ? ic[soff[k]] : 0.0f;
    }
  };
  auto storeg = [&](float (&pf)[ICB][2]) {
#pragma unroll
    for (int c = 0; c < ICB; ++c)
#pragma unroll
      for (int k = 0; k < 2; ++k)
        if (sst[k]) tile[c][sdst[k]] = pf[c][k];
  };
  const int lb = tyl * 24 + txl;
  auto computeg = [&](int g) {
#pragma unroll
    for (int c = 0; c < ICB; ++c) {
      const float* tl = &tile[c][0];
      float x00 = tl[lb],      x01 = tl[lb + 1],  x02 = tl[lb + 2];
      float x10 = tl[lb + 24], x11 = tl[lb + 25], x12 = tl[lb + 26];
      float x20 = tl[lb + 48], x21 = tl[lb + 49], x22 = tl[lb + 50];
      const float* wv = wt + ((size_t)(g * ICB + c) * Cout + o0) * 16;
#pragma unroll
      for (int j = 0; j < G; ++j) {
        const float* w4 = wv + j * 16;
        a00[j] = fmaf(x11, w4[5],  fmaf(x10, w4[7],  fmaf(x01, w4[13], fmaf(x00, w4[15], a00[j]))));
        a01[j] = fmaf(x12, w4[4],  fmaf(x11, w4[6],  fmaf(x02, w4[12], fmaf(x01, w4[14], a01[j]))));
        a10[j] = fmaf(x21, w4[1],  fmaf(x20, w4[3],  fmaf(x11, w4[9],  fmaf(x10, w4[11], a10[j]))));
        a11[j] = fmaf(x22, w4[0],  fmaf(x21, w4[2],  fmaf(x12, w4[8],  fmaf(x11, w4[10], a11[j]))));
      }
    }
  };

  loadg(0, pfA);
  for (int g = 0; g < NG; g += 2) {
    __syncthreads();
    storeg(pfA);
    if (g + 1 < NG) loadg(g + 1, pfB);
    __syncthreads();
    computeg(g);
    if (g + 1 < NG) {
      __syncthreads();
      storeg(pfB);
      if (g + 2 < NG) loadg(g + 2, pfA);
      __syncthreads();
      computeg(g + 1);
    }
  }

  size_t cs = (size_t)Hout * Wout;
  int ty = ty0 + tyl, tx = tx0 + txl;
  size_t base = ((size_t)(b * Cout + o0) * Hout + 2 * (size_t)ty) * Wout + 2 * tx;
#pragma unroll
  for (int j = 0; j < G; ++j) {
    float v00 = a00[j], v01 = a01[j], v10 = a10[j], v11 = a11[j];
    if (ACT == 1) {
      v00 = fmaxf(v00, 0.0f); v01 = fmaxf(v01, 0.0f);
      v10 = fmaxf(v10, 0.0f); v11 = fmaxf(v11, 0.0f);
    } else if (ACT == 2) {
      v00 = 1.0f / (1.0f + expf(-v00)); v01 = 1.0f / (1.0f + expf(-v01));
      v10 = 1.0f / (1.0f + expf(-v10)); v11 = 1.0f / (1.0f + expf(-v11));
    }
    *(float2*)(out + base + (size_t)j * cs)        = make_float2(v00, v01);
    *(float2*)(out + base + (size_t)j * cs + Wout) = make_float2(v10, v11);
  }
}

extern "C" void kernel_launch(void* const* d_in, const int* in_sizes, int n_in,
                              void* d_out, int out_size, void* d_ws, size_t ws_size,
                              hipStream_t stream) {
  const float* x   = (const float*)d_in[0];
  const float* ew1 = (const float*)d_in[1];
  const float* eb1 = (const float*)d_in[2];
  const float* ew2 = (const float*)d_in[3];
  const float* eb2 = (const float*)d_in[4];
  const float* ew3 = (const float*)d_in[5];
  const float* eb3 = (const float*)d_in[6];
  const float* pw  = (const float*)d_in[7];
  const float* pb  = (const float*)d_in[8];
  const float* emb = (const float*)d_in[9];
  const float* dw1 = (const float*)d_in[10];
  const float* db1 = (const float*)d_in[11];
  const float* dw2 = (const float*)d_in[12];
  const float* db2 = (const float*)d_in[13];
  const float* dw3 = (const float*)d_in[14];
  const float* db3 = (const float*)d_in[15];
  float* out = (float*)d_out;
  char* ws = (char*)d_ws;

  const size_t PER = 13107200ull;
  int CB = 32;
  while (CB > 1 && (size_t)CB * PER + 1024ull > ws_size) CB >>= 1;
  const size_t SA = (size_t)CB * 8388608ull;
  const size_t SB = (size_t)CB * 4194304ull;
  const size_t SC = (size_t)CB * 262144ull;
  float* A    = (float*)(ws);
  float* Bp   = (float*)(ws + SA);
  float* ze   = (float*)(ws + SA + SB);
  float* zq   = (float*)(ws + SA + SB + SC);
  float* part = (float*)(ws + SA + SB + 2 * SC);   // 256 floats total

  for (int c0 = 0; c0 < 32; c0 += CB) {
    const float* xc = x + (size_t)c0 * 3 * 65536;
    float* outc = out + (size_t)c0 * 3 * 65536;
    // encoder
    conv_t<3,   3, 16, 1><<<dim3(64, CB * 8),  256, 0, stream>>>(xc, ew1, eb1, A,  128, 256, 256);
    conv_t<128, 4, 16, 1><<<dim3(16, CB * 16), 256, 0, stream>>>(A,  ew2, eb2, Bp, 256, 128, 128);
    conv_t<256, 4, 16, 1><<<dim3(4,  CB * 32), 256, 0, stream>>>(Bp, ew3, eb3, A,  512, 64,  64);
    conv1x1_k<512, 4><<<dim3(4,  CB * 16), 256, 0, stream>>>(A,  pw,  pb,  ze, 64, 1024);
    // VQ
    vq_k<<<CB * 8, 128, 0, stream>>>(ze, emb, zq, part + (size_t)c0 * 8);
    // decoder
    convT_t<64,  4, 8, 1><<<dim3(4,  CB * 32), 256, 0, stream>>>(zq, dw1, db1, Bp, 256, 32,  32);
    convT_t<256, 4, 8, 1><<<dim3(16, CB * 16), 256, 0, stream>>>(Bp, dw2, db2, A,  128, 64,  64);
    convT_t<128, 4, 3, 2><<<dim3(64, CB * 1),  256, 0, stream>>>(A,  dw3, db3, outc, 3, 128, 128);
  }
  loss_fin<<<1, 256, 0, stream>>>(part, out + (size_t)(out_size - 1));
}

// Round 5
// 6311.538 us; speedup vs baseline: 3.8021x; 3.8021x over previous
//
#include <hip/hip_runtime.h>
#include <cstddef>

typedef __attribute__((ext_vector_type(8))) _Float16 half8;
typedef __attribute__((ext_vector_type(4))) float f32x4;

// ---------------------------------------------------------------------------
// VQ-VAE forward. conv2/conv3 via MFMA f16 2-term-split tap-GEMM; the rest
// stays f32 (R3-verified kernels). Encoder accuracy ~f32 (split err ~1e-6).
// ---------------------------------------------------------------------------

// Pre-split weights: W[Cout][CIN][4][4] f32 -> Wh/Wl in frag layout
// [tap][cb][k8][cout][8]  (cb = ci>>5, k8 = (ci>>3)&3, j = ci&7)
template<int CIN>
__global__ __launch_bounds__(256) void wsplit_k(
    const float* __restrict__ W, _Float16* __restrict__ Wh,
    _Float16* __restrict__ Wl, int Cout) {
  constexpr int NCB = CIN / 32;
  int idx = blockIdx.x * 256 + threadIdx.x;
  if (idx >= Cout * CIN) return;
  int ci = idx % CIN, co = idx / CIN;
  int cb = ci >> 5, k8 = (ci >> 3) & 3, j = ci & 7;
  const float* wp = W + (size_t)idx * 16;
#pragma unroll
  for (int tap = 0; tap < 16; ++tap) {
    float w = wp[tap];
    _Float16 wh = (_Float16)w;
    _Float16 wl = (_Float16)((w - (float)wh) * 2048.0f);
    size_t o = (((size_t)(tap * NCB + cb) * 4 + k8) * Cout + co) * 8 + j;
    Wh[o] = wh; Wl[o] = wl;
  }
}

// MFMA conv k4 s2 p1 (+ReLU). Block: 4 waves. Output tile: 64 cout x
// (4 rows x 16 cols). Wave w handles couts [w*16, w*16+16), all 64 spatial.
// K-loop: 32 cin per stage x 16 taps, mfma_f32_16x16x32_f16.
// A (weights) read from pre-split global (coalesced b128, 2-tap pipeline);
// B (inputs) staged in LDS as [k8][hy][parity][17] half8 slots (conflict-free).
template<int CIN, int RELU>
__global__ __launch_bounds__(256) void conv_mfma(
    const float* __restrict__ in, const _Float16* __restrict__ Whg,
    const _Float16* __restrict__ Wlg, const float* __restrict__ bias,
    float* __restrict__ out, int Cout, int Hin, int Win) {
  constexpr int NCB = CIN / 32;
  const int Hout = Hin >> 1, Wout = Win >> 1;
  const int TW = Wout >> 4;
  __shared__ half8 Bh[4 * 340], Bl[4 * 340];   // 4 k8 x (10 hy x 2 par x 17)
  const int tid = threadIdx.x;
  const int lane = tid & 63, w = tid >> 6;
  const int l15 = lane & 15, k8 = lane >> 4;
  const int tx = blockIdx.x % TW, ty = blockIdx.x / TW;
  const int cbo = blockIdx.y % (Cout >> 6);
  const int b   = blockIdx.y / (Cout >> 6);
  const int oy0 = ty << 2, ox0 = tx << 4;
  const int iy_org = 2 * oy0 - 1, ix_org = 2 * ox0 - 1;
  const int co0 = (cbo << 6) + (w << 4);
  const float* ip = in + (size_t)b * CIN * Hin * Win;

  f32x4 accM[4] = {f32x4{0,0,0,0},f32x4{0,0,0,0},f32x4{0,0,0,0},f32x4{0,0,0,0}};
  f32x4 accX[4] = {f32x4{0,0,0,0},f32x4{0,0,0,0},f32x4{0,0,0,0},f32x4{0,0,0,0}};

  const size_t tapStride = (size_t)NCB * 4 * Cout * 8;
  const size_t HW = (size_t)Hin * Win;

  for (int cb = 0; cb < NCB; ++cb) {
    __syncthreads();
    // ---- stage B: 340 spatial x 32 cin, split to f16 h/l, packed half8 ----
    for (int s = tid; s < 340; s += 256) {
      int hy = s / 34, hx = s - hy * 34;
      int iy = iy_org + hy, ix = ix_org + hx;
      bool ok = (unsigned)iy < (unsigned)Hin && (unsigned)ix < (unsigned)Win;
      const float* gp = ip + (size_t)cb * 32 * HW + (ptrdiff_t)iy * Win + ix;
      int slotBase = (hy * 2 + (hx & 1)) * 17 + (hx >> 1);
#pragma unroll
      for (int kk = 0; kk < 4; ++kk) {
        half8 vh, vl;
#pragma unroll
        for (int j = 0; j < 8; ++j) {
          float x = ok ? gp[(size_t)(kk * 8 + j) * HW] : 0.0f;
          _Float16 xh = (_Float16)x;
          _Float16 xl = (_Float16)((x - (float)xh) * 2048.0f);
          vh[j] = xh; vl[j] = xl;
        }
        Bh[kk * 340 + slotBase] = vh;
        Bl[kk * 340 + slotBase] = vl;
      }
    }
    __syncthreads();
    // ---- 16 taps, 2-tap register pipeline on A-frags ----
    const _Float16* aph = Whg + (((size_t)cb * 4 + k8) * Cout + co0 + l15) * 8;
    const _Float16* apl = Wlg + (((size_t)cb * 4 + k8) * Cout + co0 + l15) * 8;
    half8 ahA = *(const half8*)(aph);
    half8 alA = *(const half8*)(apl);
#pragma unroll
    for (int tp = 0; tp < 16; tp += 2) {
      half8 ahB = *(const half8*)(aph + (tp + 1) * tapStride);
      half8 alB = *(const half8*)(apl + (tp + 1) * tapStride);
      {
        int kh = tp >> 2, kw = tp & 3;
        int p = kw & 1, cidx = kw >> 1;
#pragma unroll
        for (int nf = 0; nf < 4; ++nf) {
          int slot = k8 * 340 + ((2 * nf + kh) * 2 + p) * 17 + l15 + cidx;
          half8 bh = Bh[slot], bl = Bl[slot];
          accM[nf] = __builtin_amdgcn_mfma_f32_16x16x32_f16(ahA, bh, accM[nf], 0, 0, 0);
          accX[nf] = __builtin_amdgcn_mfma_f32_16x16x32_f16(ahA, bl, accX[nf], 0, 0, 0);
          accX[nf] = __builtin_amdgcn_mfma_f32_16x16x32_f16(alA, bh, accX[nf], 0, 0, 0);
        }
      }
      if (tp + 2 < 16) {
        ahA = *(const half8*)(aph + (tp + 2) * tapStride);
        alA = *(const half8*)(apl + (tp + 2) * tapStride);
      }
      {
        int kh = (tp + 1) >> 2, kw = (tp + 1) & 3;
        int p = kw & 1, cidx = kw >> 1;
#pragma unroll
        for (int nf = 0; nf < 4; ++nf) {
          int slot = k8 * 340 + ((2 * nf + kh) * 2 + p) * 17 + l15 + cidx;
          half8 bh = Bh[slot], bl = Bl[slot];
          accM[nf] = __builtin_amdgcn_mfma_f32_16x16x32_f16(ahB, bh, accM[nf], 0, 0, 0);
          accX[nf] = __builtin_amdgcn_mfma_f32_16x16x32_f16(ahB, bl, accX[nf], 0, 0, 0);
          accX[nf] = __builtin_amdgcn_mfma_f32_16x16x32_f16(alB, bh, accX[nf], 0, 0, 0);
        }
      }
    }
  }
  // ---- epilogue: C row = cout (k8*4+i), col = spatial (l15) ----
#pragma unroll
  for (int nf = 0; nf < 4; ++nf) {
    int oy = oy0 + nf, ox = ox0 + l15;
#pragma unroll
    for (int i = 0; i < 4; ++i) {
      int co = co0 + k8 * 4 + i;
      float v = accM[nf][i] + accX[nf][i] * (1.0f / 2048.0f) + bias[co];
      if (RELU) v = fmaxf(v, 0.0f);
      out[(((size_t)b * Cout + co) * Hout + oy) * Wout + ox] = v;
    }
  }
}

// ---------------- R3-verified f32 kernels (unchanged) ----------------------

template<int CIN, int G, int RELU>
__global__ __launch_bounds__(256) void conv_t(
    const float* __restrict__ in, const float* __restrict__ wt,
    const float* __restrict__ bias, float* __restrict__ out,
    int Cout, int Hin, int Win) {
  const int Hout = Hin >> 1, Wout = Win >> 1;
  const int TW = Wout >> 4;
  __shared__ float tile[34 * 35];
  int tid = threadIdx.x;
  int oxl = tid & 15, oyl = tid >> 4;
  int tyt = blockIdx.x / TW, txt = blockIdx.x - tyt * TW;
  int oy0 = tyt << 4, ox0 = txt << 4;
  int cg = blockIdx.y % (Cout / G);
  int b  = blockIdx.y / (Cout / G);
  int co0 = cg * G;
  const int iy_org = 2 * oy0 - 1, ix_org = 2 * ox0 - 1;
  const float* ip = in + (size_t)b * CIN * Hin * Win;
  float acc[G];
#pragma unroll
  for (int j = 0; j < G; ++j) acc[j] = bias[co0 + j];
  const int lbase = (2 * oyl) * 35 + 2 * oxl;
  for (int ci = 0; ci < CIN; ++ci) {
    const float* ic = ip + (size_t)ci * Hin * Win;
    __syncthreads();
#pragma unroll
    for (int k = 0; k < 5; ++k) {
      int idx = tid + k * 256;
      if (idx < 34 * 34) {
        int r = idx / 34, c = idx - r * 34;
        int iy = iy_org + r, ix = ix_org + c;
        float v = ((unsigned)iy < (unsigned)Hin && (unsigned)ix < (unsigned)Win)
                      ? ic[(size_t)iy * Win + ix] : 0.0f;
        tile[r * 35 + c] = v;
      }
    }
    __syncthreads();
    float xv[16];
#pragma unroll
    for (int kh = 0; kh < 4; ++kh)
#pragma unroll
      for (int kw = 0; kw < 4; ++kw)
        xv[kh * 4 + kw] = tile[lbase + kh * 35 + kw];
    const float* wc = wt + ((size_t)co0 * CIN + ci) * 16;
#pragma unroll
    for (int j = 0; j < G; ++j) {
      const float* wj = wc + (size_t)j * CIN * 16;
#pragma unroll
      for (int t2 = 0; t2 < 16; ++t2) acc[j] = fmaf(xv[t2], wj[t2], acc[j]);
    }
  }
  size_t cs = (size_t)Hout * Wout;
  float* op = out + ((size_t)(b * Cout + co0) * Hout + (oy0 + oyl)) * Wout + ox0 + oxl;
#pragma unroll
  for (int j = 0; j < G; ++j) {
    float v = acc[j];
    if (RELU) v = fmaxf(v, 0.0f);
    op[(size_t)j * cs] = v;
  }
}

template<int CIN, int G>
__global__ __launch_bounds__(256) void conv1x1_k(
    const float* __restrict__ in, const float* __restrict__ wt,
    const float* __restrict__ bias, float* __restrict__ out,
    int Cout, int HW) {
  int hw = blockIdx.x * 256 + threadIdx.x;
  int cg = blockIdx.y % (Cout / G);
  int b  = blockIdx.y / (Cout / G);
  int co0 = cg * G;
  const float* ip = in + (size_t)b * CIN * HW + hw;
  float acc[G];
#pragma unroll
  for (int j = 0; j < G; ++j) acc[j] = bias[co0 + j];
#pragma unroll 4
  for (int ci = 0; ci < CIN; ++ci) {
    float xv = ip[(size_t)ci * HW];
#pragma unroll
    for (int j = 0; j < G; ++j)
      acc[j] = fmaf(xv, wt[(size_t)(co0 + j) * CIN + ci], acc[j]);
  }
  float* op = out + ((size_t)(b * Cout + co0)) * HW + hw;
#pragma unroll
  for (int j = 0; j < G; ++j) op[(size_t)j * HW] = acc[j];
}

__global__ __launch_bounds__(128) void vq_k(
    const float* __restrict__ ze, const float* __restrict__ emb,
    float* __restrict__ zq, float* __restrict__ partial) {
  __shared__ float4 se4[128 * 16];
  __shared__ float red[128];
  int tid = threadIdx.x;
  int gid = blockIdx.x * 128 + tid;
  int b = gid >> 10, n = gid & 1023;
  const float* zp = ze + ((size_t)b << 16) + n;
  float4 v4[16];
#pragma unroll
  for (int d = 0; d < 16; ++d) {
    v4[d].x = zp[(size_t)(4 * d + 0) << 10];
    v4[d].y = zp[(size_t)(4 * d + 1) << 10];
    v4[d].z = zp[(size_t)(4 * d + 2) << 10];
    v4[d].w = zp[(size_t)(4 * d + 3) << 10];
  }
  float best = 1e30f; int bi = 0;
  for (int c = 0; c < 4; ++c) {
    __syncthreads();
    for (int i = tid; i < 2048; i += 128)
      se4[i] = ((const float4*)emb)[(c << 11) + i];
    __syncthreads();
    for (int k = 0; k < 128; ++k) {
      const float4* e = se4 + (k << 4);
      float s = 0.0f;
#pragma unroll
      for (int d = 0; d < 16; ++d) {
        float4 ev = e[d];
        float t0 = v4[d].x - ev.x; s = fmaf(t0, t0, s);
        float t1 = v4[d].y - ev.y; s = fmaf(t1, t1, s);
        float t2 = v4[d].z - ev.z; s = fmaf(t2, t2, s);
        float t3 = v4[d].w - ev.w; s = fmaf(t3, t3, s);
      }
      if (s < best) { best = s; bi = (c << 7) + k; }
    }
  }
  const float4* eb4 = (const float4*)emb + ((size_t)bi << 4);
  float* qp = zq + ((size_t)b << 16) + n;
  float ls = 0.0f;
#pragma unroll
  for (int d = 0; d < 16; ++d) {
    float4 q = eb4[d];
    qp[(size_t)(4 * d + 0) << 10] = q.x;
    qp[(size_t)(4 * d + 1) << 10] = q.y;
    qp[(size_t)(4 * d + 2) << 10] = q.z;
    qp[(size_t)(4 * d + 3) << 10] = q.w;
    float t0 = q.x - v4[d].x; ls = fmaf(t0, t0, ls);
    float t1 = q.y - v4[d].y; ls = fmaf(t1, t1, ls);
    float t2 = q.z - v4[d].z; ls = fmaf(t2, t2, ls);
    float t3 = q.w - v4[d].w; ls = fmaf(t3, t3, ls);
  }
  red[tid] = ls;
  __syncthreads();
  for (int s = 64; s > 0; s >>= 1) {
    if (tid < s) red[tid] += red[tid + s];
    __syncthreads();
  }
  if (tid == 0) partial[blockIdx.x] = red[0];
}

__global__ __launch_bounds__(256) void loss_fin(
    const float* __restrict__ partial, float* __restrict__ out) {
  __shared__ float red[256];
  int t = threadIdx.x;
  red[t] = partial[t];
  __syncthreads();
  for (int s = 128; s > 0; s >>= 1) {
    if (t < s) red[t] += red[t + s];
    __syncthreads();
  }
  if (t == 0) out[0] = red[0] * (2.0f / 2097152.0f);
}

template<int CIN, int G, int ACT>
__global__ __launch_bounds__(256) void convT_t(
    const float* __restrict__ in, const float* __restrict__ wt,
    const float* __restrict__ bias, float* __restrict__ out,
    int Cout, int Hin, int Win) {
  const int Hout = Hin * 2, Wout = Win * 2;
  const int TW = Win >> 4;
  __shared__ float tile[18 * 19];
  int tid = threadIdx.x;
  int txl = tid & 15, tyl = tid >> 4;
  int tyt = blockIdx.x / TW, txt = blockIdx.x - tyt * TW;
  int ty0 = tyt << 4, tx0 = txt << 4;
  int og = blockIdx.y % (Cout / G);
  int b  = blockIdx.y / (Cout / G);
  int o0 = og * G;
  const int iy_org = ty0 - 1, ix_org = tx0 - 1;
  const float* ip = in + (size_t)b * CIN * Hin * Win;
  float a00[G], a01[G], a10[G], a11[G];
#pragma unroll
  for (int j = 0; j < G; ++j) {
    float bb = bias[o0 + j];
    a00[j] = bb; a01[j] = bb; a10[j] = bb; a11[j] = bb;
  }
  const int lb = tyl * 19 + txl;
  for (int i = 0; i < CIN; ++i) {
    const float* ic = ip + (size_t)i * Hin * Win;
    __syncthreads();
#pragma unroll
    for (int k = 0; k < 2; ++k) {
      int idx = tid + k * 256;
      if (idx < 18 * 18) {
        int r = idx / 18, c = idx - r * 18;
        int iy = iy_org + r, ix = ix_org + c;
        float v = ((unsigned)iy < (unsigned)Hin && (unsigned)ix < (unsigned)Win)
                      ? ic[(size_t)iy * Win + ix] : 0.0f;
        tile[r * 19 + c] = v;
      }
    }
    __syncthreads();
    float x00 = tile[lb],          x01 = tile[lb + 1],      x02 = tile[lb + 2];
    float x10 = tile[lb + 19],     x11 = tile[lb + 20],     x12 = tile[lb + 21];
    float x20 = tile[lb + 38],     x21 = tile[lb + 39],     x22 = tile[lb + 40];
    const float* wv = wt + ((size_t)i * Cout + o0) * 16;
#pragma unroll
    for (int j = 0; j < G; ++j) {
      const float* w4 = wv + j * 16;
      a00[j] = fmaf(x11, w4[5],  fmaf(x10, w4[7],  fmaf(x01, w4[13], fmaf(x00, w4[15], a00[j]))));
      a01[j] = fmaf(x12, w4[4],  fmaf(x11, w4[6],  fmaf(x02, w4[12], fmaf(x01, w4[14], a01[j]))));
      a10[j] = fmaf(x21, w4[1],  fmaf(x20, w4[3],  fmaf(x11, w4[9],  fmaf(x10, w4[11], a10[j]))));
      a11[j] = fmaf(x22, w4[0],  fmaf(x21, w4[2],  fmaf(x12, w4[8],  fmaf(x11, w4[10], a11[j]))));
    }
  }
  size_t cs = (size_t)Hout * Wout;
  int ty = ty0 + tyl, tx = tx0 + txl;
  size_t base = ((size_t)(b * Cout + o0) * Hout + 2 * (size_t)ty) * Wout + 2 * tx;
#pragma unroll
  for (int j = 0; j < G; ++j) {
    float v00 = a00[j], v01 = a01[j], v10 = a10[j], v11 = a11[j];
    if (ACT == 1) {
      v00 = fmaxf(v00, 0.0f); v01 = fmaxf(v01, 0.0f);
      v10 = fmaxf(v10, 0.0f); v11 = fmaxf(v11, 0.0f);
    } else if (ACT == 2) {
      v00 = 1.0f / (1.0f + expf(-v00)); v01 = 1.0f / (1.0f + expf(-v01));
      v10 = 1.0f / (1.0f + expf(-v10)); v11 = 1.0f / (1.0f + expf(-v11));
    }
    *(float2*)(out + base + (size_t)j * cs)        = make_float2(v00, v01);
    *(float2*)(out + base + (size_t)j * cs + Wout) = make_float2(v10, v11);
  }
}

extern "C" void kernel_launch(void* const* d_in, const int* in_sizes, int n_in,
                              void* d_out, int out_size, void* d_ws, size_t ws_size,
                              hipStream_t stream) {
  const float* x   = (const float*)d_in[0];
  const float* ew1 = (const float*)d_in[1];
  const float* eb1 = (const float*)d_in[2];
  const float* ew2 = (const float*)d_in[3];
  const float* eb2 = (const float*)d_in[4];
  const float* ew3 = (const float*)d_in[5];
  const float* eb3 = (const float*)d_in[6];
  const float* pw  = (const float*)d_in[7];
  const float* pb  = (const float*)d_in[8];
  const float* emb = (const float*)d_in[9];
  const float* dw1 = (const float*)d_in[10];
  const float* db1 = (const float*)d_in[11];
  const float* dw2 = (const float*)d_in[12];
  const float* db2 = (const float*)d_in[13];
  const float* dw3 = (const float*)d_in[14];
  const float* db3 = (const float*)d_in[15];
  float* out = (float*)d_out;
  char* ws = (char*)d_ws;

  // Per-image: region A 8388608 B, region B 4194304 B, ze/zq 262144 B each.
  // Tail: part (1KB, padded 4KB) + Wsplit (conv2 2MB, conv3 8MB).
  const size_t PER  = 13107200ull;
  const size_t WEXT = 4096ull + 2097152ull * 5ull;   // part pad + 10 MB Wsplit
  int CB = 32;
  while (CB > 1 && (size_t)CB * PER + WEXT > ws_size) CB >>= 1;
  const size_t SA = (size_t)CB * 8388608ull;
  const size_t SB = (size_t)CB * 4194304ull;
  const size_t SC = (size_t)CB * 262144ull;
  float* A    = (float*)(ws);
  float* Bp   = (float*)(ws + SA);
  float* ze   = (float*)(ws + SA + SB);
  float* zq   = (float*)(ws + SA + SB + SC);
  float* part = (float*)(ws + SA + SB + 2 * SC);           // 256 floats
  _Float16* wh2 = (_Float16*)(ws + SA + SB + 2 * SC + 4096);
  _Float16* wl2 = wh2 + 524288;    // 256*128*16
  _Float16* wh3 = wl2 + 524288;
  _Float16* wl3 = wh3 + 2097152;   // 512*256*16

  // Pre-split conv2/conv3 weights into MFMA fragment layout (f16 hi/lo).
  wsplit_k<128><<<128, 256, 0, stream>>>(ew2, wh2, wl2, 256);
  wsplit_k<256><<<512, 256, 0, stream>>>(ew3, wh3, wl3, 512);

  for (int c0 = 0; c0 < 32; c0 += CB) {
    const float* xc = x + (size_t)c0 * 3 * 65536;
    float* outc = out + (size_t)c0 * 3 * 65536;
    // encoder
    conv_t<3, 16, 1><<<dim3(64, CB * 8), 256, 0, stream>>>(xc, ew1, eb1, A, 128, 256, 256);
    conv_mfma<128, 1><<<dim3(64, CB * 4), 256, 0, stream>>>(A,  wh2, wl2, eb2, Bp, 256, 128, 128);
    conv_mfma<256, 1><<<dim3(16, CB * 8), 256, 0, stream>>>(Bp, wh3, wl3, eb3, A,  512, 64,  64);
    conv1x1_k<512, 4><<<dim3(4, CB * 16), 256, 0, stream>>>(A, pw, pb, ze, 64, 1024);
    // VQ
    vq_k<<<CB * 8, 128, 0, stream>>>(ze, emb, zq, part + (size_t)c0 * 8);
    // decoder
    convT_t<64,  8, 1><<<dim3(4,  CB * 32), 256, 0, stream>>>(zq, dw1, db1, Bp, 256, 32,  32);
    convT_t<256, 8, 1><<<dim3(16, CB * 16), 256, 0, stream>>>(Bp, dw2, db2, A,  128, 64,  64);
    convT_t<128, 3, 2><<<dim3(64, CB * 1),  256, 0, stream>>>(A,  dw3, db3, outc, 3, 128, 128);
  }
  loss_fin<<<1, 256, 0, stream>>>(part, out + (size_t)(out_size - 1));
}

// Round 6
// 3779.200 us; speedup vs baseline: 6.3497x; 1.6701x over previous
//
#include <hip/hip_runtime.h>
#include <cstddef>

typedef __attribute__((ext_vector_type(8))) _Float16 half8;
typedef __attribute__((ext_vector_type(4))) float f32x4;

// ---------------------------------------------------------------------------
// VQ-VAE forward. conv2/conv3 and convT1/convT2 via MFMA f16 2-term-split
// tap-GEMM; conv1/conv1x1/convT3 f32. Encoder accuracy ~f32 (split err ~1e-6).
// ---------------------------------------------------------------------------

// Pre-split conv weights: W[Cout][CIN][4][4] -> [tap][cb][k8][cout][8] f16 h/l
template<int CIN>
__global__ __launch_bounds__(256) void wsplit_k(
    const float* __restrict__ W, _Float16* __restrict__ Wh,
    _Float16* __restrict__ Wl, int Cout) {
  constexpr int NCB = CIN / 32;
  int idx = blockIdx.x * 256 + threadIdx.x;
  if (idx >= Cout * CIN) return;
  int ci = idx % CIN, co = idx / CIN;
  int cb = ci >> 5, k8 = (ci >> 3) & 3, j = ci & 7;
  const float* wp = W + (size_t)idx * 16;
#pragma unroll
  for (int tap = 0; tap < 16; ++tap) {
    float w = wp[tap];
    _Float16 wh = (_Float16)w;
    _Float16 wl = (_Float16)((w - (float)wh) * 2048.0f);
    size_t o = (((size_t)(tap * NCB + cb) * 4 + k8) * Cout + co) * 8 + j;
    Wh[o] = wh; Wl[o] = wl;
  }
}

// Pre-split convT weights: W[CIN][Cout][4][4] -> [t][cb][k8][cout][8] f16 h/l,
// t = (py,px,i0,i1): parity-tap enumeration matching convT_mfma's loop.
template<int CIN>
__global__ __launch_bounds__(256) void wsplitT_k(
    const float* __restrict__ W, _Float16* __restrict__ Wh,
    _Float16* __restrict__ Wl, int Cout) {
  constexpr int NCB = CIN / 32;
  int idx = blockIdx.x * 256 + threadIdx.x;
  if (idx >= CIN * Cout) return;
  int co = idx % Cout, ci = idx / Cout;
  int cb = ci >> 5, k8 = (ci >> 3) & 3, j = ci & 7;
  const float* wp = W + (size_t)idx * 16;
#pragma unroll
  for (int t = 0; t < 16; ++t) {
    int py = (t >> 3) & 1, px = (t >> 2) & 1, i0 = (t >> 1) & 1, i1 = t & 1;
    int kh = py ? (i0 ? 2 : 0) : (i0 ? 3 : 1);
    int kw = px ? (i1 ? 2 : 0) : (i1 ? 3 : 1);
    float w = wp[kh * 4 + kw];
    _Float16 wh = (_Float16)w;
    _Float16 wl = (_Float16)((w - (float)wh) * 2048.0f);
    size_t o = (((size_t)(t * NCB + cb) * 4 + k8) * Cout + co) * 8 + j;
    Wh[o] = wh; Wl[o] = wl;
  }
}

// MFMA conv k4 s2 p1 (+ReLU). (validated R5)
template<int CIN, int RELU>
__global__ __launch_bounds__(256) void conv_mfma(
    const float* __restrict__ in, const _Float16* __restrict__ Whg,
    const _Float16* __restrict__ Wlg, const float* __restrict__ bias,
    float* __restrict__ out, int Cout, int Hin, int Win) {
  constexpr int NCB = CIN / 32;
  const int Hout = Hin >> 1, Wout = Win >> 1;
  const int TW = Wout >> 4;
  __shared__ half8 Bh[4 * 340], Bl[4 * 340];
  const int tid = threadIdx.x;
  const int lane = tid & 63, w = tid >> 6;
  const int l15 = lane & 15, k8 = lane >> 4;
  const int tx = blockIdx.x % TW, ty = blockIdx.x / TW;
  const int cbo = blockIdx.y % (Cout >> 6);
  const int b   = blockIdx.y / (Cout >> 6);
  const int oy0 = ty << 2, ox0 = tx << 4;
  const int iy_org = 2 * oy0 - 1, ix_org = 2 * ox0 - 1;
  const int co0 = (cbo << 6) + (w << 4);
  const float* ip = in + (size_t)b * CIN * Hin * Win;

  f32x4 accM[4] = {f32x4{0,0,0,0},f32x4{0,0,0,0},f32x4{0,0,0,0},f32x4{0,0,0,0}};
  f32x4 accX[4] = {f32x4{0,0,0,0},f32x4{0,0,0,0},f32x4{0,0,0,0},f32x4{0,0,0,0}};

  const size_t tapStride = (size_t)NCB * 4 * Cout * 8;
  const size_t HW = (size_t)Hin * Win;

  for (int cb = 0; cb < NCB; ++cb) {
    __syncthreads();
    for (int s = tid; s < 340; s += 256) {
      int hy = s / 34, hx = s - hy * 34;
      int iy = iy_org + hy, ix = ix_org + hx;
      bool ok = (unsigned)iy < (unsigned)Hin && (unsigned)ix < (unsigned)Win;
      const float* gp = ip + (size_t)cb * 32 * HW + (ptrdiff_t)iy * Win + ix;
      int slotBase = (hy * 2 + (hx & 1)) * 17 + (hx >> 1);
#pragma unroll
      for (int kk = 0; kk < 4; ++kk) {
        half8 vh, vl;
#pragma unroll
        for (int j = 0; j < 8; ++j) {
          float x = ok ? gp[(size_t)(kk * 8 + j) * HW] : 0.0f;
          _Float16 xh = (_Float16)x;
          _Float16 xl = (_Float16)((x - (float)xh) * 2048.0f);
          vh[j] = xh; vl[j] = xl;
        }
        Bh[kk * 340 + slotBase] = vh;
        Bl[kk * 340 + slotBase] = vl;
      }
    }
    __syncthreads();
    const _Float16* aph = Whg + (((size_t)cb * 4 + k8) * Cout + co0 + l15) * 8;
    const _Float16* apl = Wlg + (((size_t)cb * 4 + k8) * Cout + co0 + l15) * 8;
    half8 ahA = *(const half8*)(aph);
    half8 alA = *(const half8*)(apl);
#pragma unroll
    for (int tp = 0; tp < 16; tp += 2) {
      half8 ahB = *(const half8*)(aph + (tp + 1) * tapStride);
      half8 alB = *(const half8*)(apl + (tp + 1) * tapStride);
      {
        int kh = tp >> 2, kw = tp & 3;
        int p = kw & 1, cidx = kw >> 1;
#pragma unroll
        for (int nf = 0; nf < 4; ++nf) {
          int slot = k8 * 340 + ((2 * nf + kh) * 2 + p) * 17 + l15 + cidx;
          half8 bh = Bh[slot], bl = Bl[slot];
          accM[nf] = __builtin_amdgcn_mfma_f32_16x16x32_f16(ahA, bh, accM[nf], 0, 0, 0);
          accX[nf] = __builtin_amdgcn_mfma_f32_16x16x32_f16(ahA, bl, accX[nf], 0, 0, 0);
          accX[nf] = __builtin_amdgcn_mfma_f32_16x16x32_f16(alA, bh, accX[nf], 0, 0, 0);
        }
      }
      if (tp + 2 < 16) {
        ahA = *(const half8*)(aph + (tp + 2) * tapStride);
        alA = *(const half8*)(apl + (tp + 2) * tapStride);
      }
      {
        int kh = (tp + 1) >> 2, kw = (tp + 1) & 3;
        int p = kw & 1, cidx = kw >> 1;
#pragma unroll
        for (int nf = 0; nf < 4; ++nf) {
          int slot = k8 * 340 + ((2 * nf + kh) * 2 + p) * 17 + l15 + cidx;
          half8 bh = Bh[slot], bl = Bl[slot];
          accM[nf] = __builtin_amdgcn_mfma_f32_16x16x32_f16(ahB, bh, accM[nf], 0, 0, 0);
          accX[nf] = __builtin_amdgcn_mfma_f32_16x16x32_f16(ahB, bl, accX[nf], 0, 0, 0);
          accX[nf] = __builtin_amdgcn_mfma_f32_16x16x32_f16(alB, bh, accX[nf], 0, 0, 0);
        }
      }
    }
  }
#pragma unroll
  for (int nf = 0; nf < 4; ++nf) {
    int oy = oy0 + nf, ox = ox0 + l15;
#pragma unroll
    for (int i = 0; i < 4; ++i) {
      int co = co0 + k8 * 4 + i;
      float v = accM[nf][i] + accX[nf][i] * (1.0f / 2048.0f) + bias[co];
      if (RELU) v = fmaxf(v, 0.0f);
      out[(((size_t)b * Cout + co) * Hout + oy) * Wout + ox] = v;
    }
  }
}

// MFMA convT k4 s2 p1 (+ReLU). Parity decomposition: 16 (parity,tap) passes.
// Block: 4 waves = 64 couts; spatial: 2 input rows x 16 cols -> 4x32 outputs.
// B staged per 32-cin block as [k8][4 rows][18 cols] half8 h/l slots.
template<int CIN, int RELU>
__global__ __launch_bounds__(256) void convT_mfma(
    const float* __restrict__ in, const _Float16* __restrict__ Whg,
    const _Float16* __restrict__ Wlg, const float* __restrict__ bias,
    float* __restrict__ out, int Cout, int Hin, int Win) {
  constexpr int NCB = CIN / 32;
  const int Hout = Hin * 2, Wout = Win * 2;
  const int TW = Win >> 4;
  __shared__ half8 Bh[4 * 72], Bl[4 * 72];
  const int tid = threadIdx.x;
  const int lane = tid & 63, w = tid >> 6;
  const int l15 = lane & 15, k8 = lane >> 4;
  const int tx = blockIdx.x % TW, ty = blockIdx.x / TW;
  const int cbo = blockIdx.y % (Cout >> 6);
  const int b   = blockIdx.y / (Cout >> 6);
  const int ty0 = ty << 1, tx0 = tx << 4;
  const int co0 = (cbo << 6) + (w << 4);
  const float* ip = in + (size_t)b * CIN * Hin * Win;
  const size_t HW = (size_t)Hin * Win;
  const size_t tapStride = (size_t)NCB * 4 * Cout * 8;

  f32x4 accM[4][2], accX[4][2];
#pragma unroll
  for (int p = 0; p < 4; ++p)
#pragma unroll
    for (int nf = 0; nf < 2; ++nf) {
      accM[p][nf] = f32x4{0,0,0,0};
      accX[p][nf] = f32x4{0,0,0,0};
    }

  for (int cb = 0; cb < NCB; ++cb) {
    __syncthreads();
    // stage 72 positions (4 rows x 18 cols halo) x 32 cin
    for (int u = tid; u < 288; u += 256) {
      int pos = u % 72, kk = u / 72;
      int r = pos / 18, c = pos - r * 18;
      int iy = ty0 - 1 + r, ix = tx0 - 1 + c;
      bool ok = (unsigned)iy < (unsigned)Hin && (unsigned)ix < (unsigned)Win;
      const float* gp = ip + ((size_t)cb * 32 + kk * 8) * HW + (ptrdiff_t)iy * Win + ix;
      half8 vh, vl;
#pragma unroll
      for (int j = 0; j < 8; ++j) {
        float x = ok ? gp[(size_t)j * HW] : 0.0f;
        _Float16 xh = (_Float16)x;
        vh[j] = xh; vl[j] = (_Float16)((x - (float)xh) * 2048.0f);
      }
      Bh[kk * 72 + pos] = vh;
      Bl[kk * 72 + pos] = vl;
    }
    __syncthreads();
    const _Float16* aph = Whg + (((size_t)cb * 4 + k8) * Cout + co0 + l15) * 8;
    const _Float16* apl = Wlg + (((size_t)cb * 4 + k8) * Cout + co0 + l15) * 8;
    half8 ahA = *(const half8*)(aph);
    half8 alA = *(const half8*)(apl);
#pragma unroll
    for (int t = 0; t < 16; ++t) {
      half8 ahN, alN;
      if (t < 15) {
        ahN = *(const half8*)(aph + (size_t)(t + 1) * tapStride);
        alN = *(const half8*)(apl + (size_t)(t + 1) * tapStride);
      }
      const int py = (t >> 3) & 1, px = (t >> 2) & 1;
      const int i0 = (t >> 1) & 1, i1 = t & 1;
      const int dy = py ? (i0 ? 0 : 1) : (i0 ? -1 : 0);
      const int dx = px ? (i1 ? 0 : 1) : (i1 ? -1 : 0);
      const int p = py * 2 + px;
#pragma unroll
      for (int nf = 0; nf < 2; ++nf) {
        int slot = k8 * 72 + (nf + 1 + dy) * 18 + (l15 + 1 + dx);
        half8 bh = Bh[slot], bl = Bl[slot];
        accM[p][nf] = __builtin_amdgcn_mfma_f32_16x16x32_f16(ahA, bh, accM[p][nf], 0, 0, 0);
        accX[p][nf] = __builtin_amdgcn_mfma_f32_16x16x32_f16(ahA, bl, accX[p][nf], 0, 0, 0);
        accX[p][nf] = __builtin_amdgcn_mfma_f32_16x16x32_f16(alA, bh, accX[p][nf], 0, 0, 0);
      }
      if (t < 15) { ahA = ahN; alA = alN; }
    }
  }
  // epilogue: row=cout(k8*4+i), col=spatial(l15); pack px pair as float2
#pragma unroll
  for (int nf = 0; nf < 2; ++nf) {
#pragma unroll
    for (int i = 0; i < 4; ++i) {
      int co = co0 + k8 * 4 + i;
      float bb = bias[co];
#pragma unroll
      for (int py = 0; py < 2; ++py) {
        float v0 = accM[py * 2 + 0][nf][i] + accX[py * 2 + 0][nf][i] * (1.0f / 2048.0f) + bb;
        float v1 = accM[py * 2 + 1][nf][i] + accX[py * 2 + 1][nf][i] * (1.0f / 2048.0f) + bb;
        if (RELU) { v0 = fmaxf(v0, 0.0f); v1 = fmaxf(v1, 0.0f); }
        int oy = 2 * (ty0 + nf) + py, ox = 2 * (tx0 + l15);
        *(float2*)(out + (((size_t)b * Cout + co) * Hout + oy) * Wout + ox) =
            make_float2(v0, v1);
      }
    }
  }
}

// ---------------- f32 kernels (R3-verified, unchanged) ---------------------

template<int CIN, int G, int RELU>
__global__ __launch_bounds__(256) void conv_t(
    const float* __restrict__ in, const float* __restrict__ wt,
    const float* __restrict__ bias, float* __restrict__ out,
    int Cout, int Hin, int Win) {
  const int Hout = Hin >> 1, Wout = Win >> 1;
  const int TW = Wout >> 4;
  __shared__ float tile[34 * 35];
  int tid = threadIdx.x;
  int oxl = tid & 15, oyl = tid >> 4;
  int tyt = blockIdx.x / TW, txt = blockIdx.x - tyt * TW;
  int oy0 = tyt << 4, ox0 = txt << 4;
  int cg = blockIdx.y % (Cout / G);
  int b  = blockIdx.y / (Cout / G);
  int co0 = cg * G;
  const int iy_org = 2 * oy0 - 1, ix_org = 2 * ox0 - 1;
  const float* ip = in + (size_t)b * CIN * Hin * Win;
  float acc[G];
#pragma unroll
  for (int j = 0; j < G; ++j) acc[j] = bias[co0 + j];
  const int lbase = (2 * oyl) * 35 + 2 * oxl;
  for (int ci = 0; ci < CIN; ++ci) {
    const float* ic = ip + (size_t)ci * Hin * Win;
    __syncthreads();
#pragma unroll
    for (int k = 0; k < 5; ++k) {
      int idx = tid + k * 256;
      if (idx < 34 * 34) {
        int r = idx / 34, c = idx - r * 34;
        int iy = iy_org + r, ix = ix_org + c;
        float v = ((unsigned)iy < (unsigned)Hin && (unsigned)ix < (unsigned)Win)
                      ? ic[(size_t)iy * Win + ix] : 0.0f;
        tile[r * 35 + c] = v;
      }
    }
    __syncthreads();
    float xv[16];
#pragma unroll
    for (int kh = 0; kh < 4; ++kh)
#pragma unroll
      for (int kw = 0; kw < 4; ++kw)
        xv[kh * 4 + kw] = tile[lbase + kh * 35 + kw];
    const float* wc = wt + ((size_t)co0 * CIN + ci) * 16;
#pragma unroll
    for (int j = 0; j < G; ++j) {
      const float* wj = wc + (size_t)j * CIN * 16;
#pragma unroll
      for (int t2 = 0; t2 < 16; ++t2) acc[j] = fmaf(xv[t2], wj[t2], acc[j]);
    }
  }
  size_t cs = (size_t)Hout * Wout;
  float* op = out + ((size_t)(b * Cout + co0) * Hout + (oy0 + oyl)) * Wout + ox0 + oxl;
#pragma unroll
  for (int j = 0; j < G; ++j) {
    float v = acc[j];
    if (RELU) v = fmaxf(v, 0.0f);
    op[(size_t)j * cs] = v;
  }
}

template<int CIN, int G>
__global__ __launch_bounds__(256) void conv1x1_k(
    const float* __restrict__ in, const float* __restrict__ wt,
    const float* __restrict__ bias, float* __restrict__ out,
    int Cout, int HW) {
  int hw = blockIdx.x * 256 + threadIdx.x;
  int cg = blockIdx.y % (Cout / G);
  int b  = blockIdx.y / (Cout / G);
  int co0 = cg * G;
  const float* ip = in + (size_t)b * CIN * HW + hw;
  float acc[G];
#pragma unroll
  for (int j = 0; j < G; ++j) acc[j] = bias[co0 + j];
#pragma unroll 4
  for (int ci = 0; ci < CIN; ++ci) {
    float xv = ip[(size_t)ci * HW];
#pragma unroll
    for (int j = 0; j < G; ++j)
      acc[j] = fmaf(xv, wt[(size_t)(co0 + j) * CIN + ci], acc[j]);
  }
  float* op = out + ((size_t)(b * Cout + co0)) * HW + hw;
#pragma unroll
  for (int j = 0; j < G; ++j) op[(size_t)j * HW] = acc[j];
}

__global__ __launch_bounds__(128) void vq_k(
    const float* __restrict__ ze, const float* __restrict__ emb,
    float* __restrict__ zq, float* __restrict__ partial) {
  __shared__ float4 se4[128 * 16];
  __shared__ float red[128];
  int tid = threadIdx.x;
  int gid = blockIdx.x * 128 + tid;
  int b = gid >> 10, n = gid & 1023;
  const float* zp = ze + ((size_t)b << 16) + n;
  float4 v4[16];
#pragma unroll
  for (int d = 0; d < 16; ++d) {
    v4[d].x = zp[(size_t)(4 * d + 0) << 10];
    v4[d].y = zp[(size_t)(4 * d + 1) << 10];
    v4[d].z = zp[(size_t)(4 * d + 2) << 10];
    v4[d].w = zp[(size_t)(4 * d + 3) << 10];
  }
  float best = 1e30f; int bi = 0;
  for (int c = 0; c < 4; ++c) {
    __syncthreads();
    for (int i = tid; i < 2048; i += 128)
      se4[i] = ((const float4*)emb)[(c << 11) + i];
    __syncthreads();
    for (int k = 0; k < 128; ++k) {
      const float4* e = se4 + (k << 4);
      float s = 0.0f;
#pragma unroll
      for (int d = 0; d < 16; ++d) {
        float4 ev = e[d];
        float t0 = v4[d].x - ev.x; s = fmaf(t0, t0, s);
        float t1 = v4[d].y - ev.y; s = fmaf(t1, t1, s);
        float t2 = v4[d].z - ev.z; s = fmaf(t2, t2, s);
        float t3 = v4[d].w - ev.w; s = fmaf(t3, t3, s);
      }
      if (s < best) { best = s; bi = (c << 7) + k; }
    }
  }
  const float4* eb4 = (const float4*)emb + ((size_t)bi << 4);
  float* qp = zq + ((size_t)b << 16) + n;
  float ls = 0.0f;
#pragma unroll
  for (int d = 0; d < 16; ++d) {
    float4 q = eb4[d];
    qp[(size_t)(4 * d + 0) << 10] = q.x;
    qp[(size_t)(4 * d + 1) << 10] = q.y;
    qp[(size_t)(4 * d + 2) << 10] = q.z;
    qp[(size_t)(4 * d + 3) << 10] = q.w;
    float t0 = q.x - v4[d].x; ls = fmaf(t0, t0, ls);
    float t1 = q.y - v4[d].y; ls = fmaf(t1, t1, ls);
    float t2 = q.z - v4[d].z; ls = fmaf(t2, t2, ls);
    float t3 = q.w - v4[d].w; ls = fmaf(t3, t3, ls);
  }
  red[tid] = ls;
  __syncthreads();
  for (int s = 64; s > 0; s >>= 1) {
    if (tid < s) red[tid] += red[tid + s];
    __syncthreads();
  }
  if (tid == 0) partial[blockIdx.x] = red[0];
}

__global__ __launch_bounds__(256) void loss_fin(
    const float* __restrict__ partial, float* __restrict__ out) {
  __shared__ float red[256];
  int t = threadIdx.x;
  red[t] = partial[t];
  __syncthreads();
  for (int s = 128; s > 0; s >>= 1) {
    if (t < s) red[t] += red[t + s];
    __syncthreads();
  }
  if (t == 0) out[0] = red[0] * (2.0f / 2097152.0f);
}

template<int CIN, int G, int ACT>
__global__ __launch_bounds__(256) void convT_t(
    const float* __restrict__ in, const float* __restrict__ wt,
    const float* __restrict__ bias, float* __restrict__ out,
    int Cout, int Hin, int Win) {
  const int Hout = Hin * 2, Wout = Win * 2;
  const int TW = Win >> 4;
  __shared__ float tile[18 * 19];
  int tid = threadIdx.x;
  int txl = tid & 15, tyl = tid >> 4;
  int tyt = blockIdx.x / TW, txt = blockIdx.x - tyt * TW;
  int ty0 = tyt << 4, tx0 = txt << 4;
  int og = blockIdx.y % (Cout / G);
  int b  = blockIdx.y / (Cout / G);
  int o0 = og * G;
  const int iy_org = ty0 - 1, ix_org = tx0 - 1;
  const float* ip = in + (size_t)b * CIN * Hin * Win;
  float a00[G], a01[G], a10[G], a11[G];
#pragma unroll
  for (int j = 0; j < G; ++j) {
    float bb = bias[o0 + j];
    a00[j] = bb; a01[j] = bb; a10[j] = bb; a11[j] = bb;
  }
  const int lb = tyl * 19 + txl;
  for (int i = 0; i < CIN; ++i) {
    const float* ic = ip + (size_t)i * Hin * Win;
    __syncthreads();
#pragma unroll
    for (int k = 0; k < 2; ++k) {
      int idx = tid + k * 256;
      if (idx < 18 * 18) {
        int r = idx / 18, c = idx - r * 18;
        int iy = iy_org + r, ix = ix_org + c;
        float v = ((unsigned)iy < (unsigned)Hin && (unsigned)ix < (unsigned)Win)
                      ? ic[(size_t)iy * Win + ix] : 0.0f;
        tile[r * 19 + c] = v;
      }
    }
    __syncthreads();
    float x00 = tile[lb],          x01 = tile[lb + 1],      x02 = tile[lb + 2];
    float x10 = tile[lb + 19],     x11 = tile[lb + 20],     x12 = tile[lb + 21];
    float x20 = tile[lb + 38],     x21 = tile[lb + 39],     x22 = tile[lb + 40];
    const float* wv = wt + ((size_t)i * Cout + o0) * 16;
#pragma unroll
    for (int j = 0; j < G; ++j) {
      const float* w4 = wv + j * 16;
      a00[j] = fmaf(x11, w4[5],  fmaf(x10, w4[7],  fmaf(x01, w4[13], fmaf(x00, w4[15], a00[j]))));
      a01[j] = fmaf(x12, w4[4],  fmaf(x11, w4[6],  fmaf(x02, w4[12], fmaf(x01, w4[14], a01[j]))));
      a10[j] = fmaf(x21, w4[1],  fmaf(x20, w4[3],  fmaf(x11, w4[9],  fmaf(x10, w4[11], a10[j]))));
      a11[j] = fmaf(x22, w4[0],  fmaf(x21, w4[2],  fmaf(x12, w4[8],  fmaf(x11, w4[10], a11[j]))));
    }
  }
  size_t cs = (size_t)Hout * Wout;
  int ty = ty0 + tyl, tx = tx0 + txl;
  size_t base = ((size_t)(b * Cout + o0) * Hout + 2 * (size_t)ty) * Wout + 2 * tx;
#pragma unroll
  for (int j = 0; j < G; ++j) {
    float v00 = a00[j], v01 = a01[j], v10 = a10[j], v11 = a11[j];
    if (ACT == 1) {
      v00 = fmaxf(v00, 0.0f); v01 = fmaxf(v01, 0.0f);
      v10 = fmaxf(v10, 0.0f); v11 = fmaxf(v11, 0.0f);
    } else if (ACT == 2) {
      v00 = 1.0f / (1.0f + expf(-v00)); v01 = 1.0f / (1.0f + expf(-v01));
      v10 = 1.0f / (1.0f + expf(-v10)); v11 = 1.0f / (1.0f + expf(-v11));
    }
    *(float2*)(out + base + (size_t)j * cs)        = make_float2(v00, v01);
    *(float2*)(out + base + (size_t)j * cs + Wout) = make_float2(v10, v11);
  }
}

extern "C" void kernel_launch(void* const* d_in, const int* in_sizes, int n_in,
                              void* d_out, int out_size, void* d_ws, size_t ws_size,
                              hipStream_t stream) {
  const float* x   = (const float*)d_in[0];
  const float* ew1 = (const float*)d_in[1];
  const float* eb1 = (const float*)d_in[2];
  const float* ew2 = (const float*)d_in[3];
  const float* eb2 = (const float*)d_in[4];
  const float* ew3 = (const float*)d_in[5];
  const float* eb3 = (const float*)d_in[6];
  const float* pw  = (const float*)d_in[7];
  const float* pb  = (const float*)d_in[8];
  const float* emb = (const float*)d_in[9];
  const float* dw1 = (const float*)d_in[10];
  const float* db1 = (const float*)d_in[11];
  const float* dw2 = (const float*)d_in[12];
  const float* db2 = (const float*)d_in[13];
  const float* dw3 = (const float*)d_in[14];
  const float* db3 = (const float*)d_in[15];
  float* out = (float*)d_out;
  char* ws = (char*)d_ws;

  // Per-image: region A 8 MB, region B 4 MB, ze/zq 256 KB each.
  // Tail: part pad 4 KB + weight splits 13 MB.
  const size_t PER  = 13107200ull;
  const size_t WEXT = 4096ull + 13631488ull;
  int CB = 32;
  while (CB > 1 && (size_t)CB * PER + WEXT > ws_size) CB >>= 1;
  const size_t SA = (size_t)CB * 8388608ull;
  const size_t SB = (size_t)CB * 4194304ull;
  const size_t SC = (size_t)CB * 262144ull;
  float* A    = (float*)(ws);
  float* Bp   = (float*)(ws + SA);
  float* ze   = (float*)(ws + SA + SB);
  float* zq   = (float*)(ws + SA + SB + SC);
  float* part = (float*)(ws + SA + SB + 2 * SC);           // 256 floats
  _Float16* wh2  = (_Float16*)(ws + SA + SB + 2 * SC + 4096);
  _Float16* wl2  = wh2 + 524288;    // conv2: 256*128*16
  _Float16* wh3  = wl2 + 524288;
  _Float16* wl3  = wh3 + 2097152;   // conv3: 512*256*16
  _Float16* whT1 = wl3 + 2097152;
  _Float16* wlT1 = whT1 + 262144;   // convT1: 64*256*16
  _Float16* whT2 = wlT1 + 262144;
  _Float16* wlT2 = whT2 + 524288;   // convT2: 256*128*16

  // Pre-split weights into MFMA fragment layout (f16 hi/lo).
  wsplit_k<128><<<128, 256, 0, stream>>>(ew2, wh2, wl2, 256);
  wsplit_k<256><<<512, 256, 0, stream>>>(ew3, wh3, wl3, 512);
  wsplitT_k<64><<<64,  256, 0, stream>>>(dw1, whT1, wlT1, 256);
  wsplitT_k<256><<<128, 256, 0, stream>>>(dw2, whT2, wlT2, 128);

  for (int c0 = 0; c0 < 32; c0 += CB) {
    const float* xc = x + (size_t)c0 * 3 * 65536;
    float* outc = out + (size_t)c0 * 3 * 65536;
    // encoder
    conv_t<3, 16, 1><<<dim3(64, CB * 8), 256, 0, stream>>>(xc, ew1, eb1, A, 128, 256, 256);
    conv_mfma<128, 1><<<dim3(64, CB * 4), 256, 0, stream>>>(A,  wh2, wl2, eb2, Bp, 256, 128, 128);
    conv_mfma<256, 1><<<dim3(16, CB * 8), 256, 0, stream>>>(Bp, wh3, wl3, eb3, A,  512, 64,  64);
    conv1x1_k<512, 4><<<dim3(4, CB * 16), 256, 0, stream>>>(A, pw, pb, ze, 64, 1024);
    // VQ
    vq_k<<<CB * 8, 128, 0, stream>>>(ze, emb, zq, part + (size_t)c0 * 8);
    // decoder: convT1/convT2 MFMA, convT3 f32
    convT_mfma<64,  1><<<dim3(32,  CB * 4), 256, 0, stream>>>(zq, whT1, wlT1, db1, Bp, 256, 32, 32);
    convT_mfma<256, 1><<<dim3(128, CB * 2), 256, 0, stream>>>(Bp, whT2, wlT2, db2, A, 128, 64, 64);
    convT_t<128, 3, 2><<<dim3(64, CB * 1), 256, 0, stream>>>(A, dw3, db3, outc, 3, 128, 128);
  }
  loss_fin<<<1, 256, 0, stream>>>(part, out + (size_t)(out_size - 1));
}

// Round 7
// 2572.832 us; speedup vs baseline: 9.3270x; 1.4689x over previous
//
#include <hip/hip_runtime.h>
#include <cstddef>

typedef __attribute__((ext_vector_type(8))) _Float16 half8;
typedef __attribute__((ext_vector_type(4))) float f32x4;

// ---------------------------------------------------------------------------
// VQ-VAE forward. conv2/conv3 and convT1/convT2 via MFMA f16 2-term-split
// tap-GEMM; conv1/conv1x1/convT3 f32. Encoder accuracy ~f32 (split err ~1e-6).
// R7: conv_mfma2 — all couts per block (B-tile reuse), A 2-deep pipeline,
// LDS k8 pad 346. Math order identical to R5/R6 (bit-identical outputs).
// ---------------------------------------------------------------------------

// Pre-split conv weights: W[Cout][CIN][4][4] -> [tap][cb][k8][cout][8] f16 h/l
template<int CIN>
__global__ __launch_bounds__(256) void wsplit_k(
    const float* __restrict__ W, _Float16* __restrict__ Wh,
    _Float16* __restrict__ Wl, int Cout) {
  constexpr int NCB = CIN / 32;
  int idx = blockIdx.x * 256 + threadIdx.x;
  if (idx >= Cout * CIN) return;
  int ci = idx % CIN, co = idx / CIN;
  int cb = ci >> 5, k8 = (ci >> 3) & 3, j = ci & 7;
  const float* wp = W + (size_t)idx * 16;
#pragma unroll
  for (int tap = 0; tap < 16; ++tap) {
    float w = wp[tap];
    _Float16 wh = (_Float16)w;
    _Float16 wl = (_Float16)((w - (float)wh) * 2048.0f);
    size_t o = (((size_t)(tap * NCB + cb) * 4 + k8) * Cout + co) * 8 + j;
    Wh[o] = wh; Wl[o] = wl;
  }
}

// Pre-split convT weights: W[CIN][Cout][4][4] -> [t][cb][k8][cout][8] f16 h/l
template<int CIN>
__global__ __launch_bounds__(256) void wsplitT_k(
    const float* __restrict__ W, _Float16* __restrict__ Wh,
    _Float16* __restrict__ Wl, int Cout) {
  constexpr int NCB = CIN / 32;
  int idx = blockIdx.x * 256 + threadIdx.x;
  if (idx >= CIN * Cout) return;
  int co = idx % Cout, ci = idx / Cout;
  int cb = ci >> 5, k8 = (ci >> 3) & 3, j = ci & 7;
  const float* wp = W + (size_t)idx * 16;
#pragma unroll
  for (int t = 0; t < 16; ++t) {
    int py = (t >> 3) & 1, px = (t >> 2) & 1, i0 = (t >> 1) & 1, i1 = t & 1;
    int kh = py ? (i0 ? 2 : 0) : (i0 ? 3 : 1);
    int kw = px ? (i1 ? 2 : 0) : (i1 ? 3 : 1);
    float w = wp[kh * 4 + kw];
    _Float16 wh = (_Float16)w;
    _Float16 wl = (_Float16)((w - (float)wh) * 2048.0f);
    size_t o = (((size_t)(t * NCB + cb) * 4 + k8) * Cout + co) * 8 + j;
    Wh[o] = wh; Wl[o] = wl;
  }
}

// MFMA conv k4 s2 p1 (+ReLU), R7 structure.
// Block: 4 waves; computes MT=COUT/CGRP couts x (4 rows x 16 cols) outputs.
// Wave w owns MF=MT/64 M-frags. B staged once per cb, reused by all M-frags.
template<int CIN, int COUT, int CGRP, int RELU>
__global__ __launch_bounds__(256) void conv_mfma2(
    const float* __restrict__ in, const _Float16* __restrict__ Whg,
    const _Float16* __restrict__ Wlg, const float* __restrict__ bias,
    float* __restrict__ out, int Hin, int Win) {
  constexpr int NCB = CIN / 32;
  constexpr int MT  = COUT / CGRP;
  constexpr int MF  = MT / 64;       // M-frags per wave
  const int Hout = Hin >> 1, Wout = Win >> 1;
  const int TW = Wout >> 4;
  __shared__ half8 Bh[4 * 346], Bl[4 * 346];   // k8-stride 346 (bank stagger)
  const int tid = threadIdx.x;
  const int lane = tid & 63, w = tid >> 6;
  const int l15 = lane & 15, k8 = lane >> 4;
  const int tx = blockIdx.x % TW, ty = blockIdx.x / TW;
  const int cg = blockIdx.y % CGRP;
  const int b  = blockIdx.y / CGRP;
  const int oy0 = ty << 2, ox0 = tx << 4;
  const int iy_org = 2 * oy0 - 1, ix_org = 2 * ox0 - 1;
  const int cbase = cg * MT + w * (MT / 4);
  const float* ip = in + (size_t)b * CIN * Hin * Win;
  const size_t tapStride = (size_t)NCB * 4 * COUT * 8;
  const size_t HW = (size_t)Hin * Win;

  f32x4 accM[MF][4], accX[MF][4];
#pragma unroll
  for (int m = 0; m < MF; ++m)
#pragma unroll
    for (int nf = 0; nf < 4; ++nf) {
      accM[m][nf] = f32x4{0,0,0,0};
      accX[m][nf] = f32x4{0,0,0,0};
    }

  for (int cb = 0; cb < NCB; ++cb) {
    __syncthreads();
    // ---- stage B: 340 positions x 32 cin, f16 h/l split, half8 slots ----
    for (int s = tid; s < 340; s += 256) {
      int hy = s / 34, hx = s - hy * 34;
      int iy = iy_org + hy, ix = ix_org + hx;
      bool ok = (unsigned)iy < (unsigned)Hin && (unsigned)ix < (unsigned)Win;
      const float* gp = ip + (size_t)cb * 32 * HW + (ptrdiff_t)iy * Win + ix;
      int slotBase = (hy * 2 + (hx & 1)) * 17 + (hx >> 1);
#pragma unroll
      for (int kk = 0; kk < 4; ++kk) {
        half8 vh, vl;
#pragma unroll
        for (int j = 0; j < 8; ++j) {
          float x = ok ? gp[(size_t)(kk * 8 + j) * HW] : 0.0f;
          _Float16 xh = (_Float16)x;
          vh[j] = xh; vl[j] = (_Float16)((x - (float)xh) * 2048.0f);
        }
        Bh[kk * 346 + slotBase] = vh;
        Bl[kk * 346 + slotBase] = vl;
      }
    }
    __syncthreads();
    // ---- 16 taps; A-frags (MF per wave) in 2-deep register pipeline ----
    const _Float16* aph = Whg + (((size_t)cb * 4 + k8) * COUT + cbase + l15) * 8;
    const _Float16* apl = Wlg + (((size_t)cb * 4 + k8) * COUT + cbase + l15) * 8;
    half8 ah[2][MF], al[2][MF];
#pragma unroll
    for (int m = 0; m < MF; ++m) {
      ah[0][m] = *(const half8*)(aph + m * 128);
      al[0][m] = *(const half8*)(apl + m * 128);
    }
#pragma unroll
    for (int tp = 0; tp < 16; ++tp) {
      const int cur = tp & 1, nxt = cur ^ 1;
      if (tp < 15) {
#pragma unroll
        for (int m = 0; m < MF; ++m) {
          ah[nxt][m] = *(const half8*)(aph + (size_t)(tp + 1) * tapStride + m * 128);
          al[nxt][m] = *(const half8*)(apl + (size_t)(tp + 1) * tapStride + m * 128);
        }
      }
      const int kh = tp >> 2, kw = tp & 3;
      const int p = kw & 1, cidx = kw >> 1;
#pragma unroll
      for (int nf = 0; nf < 4; ++nf) {
        const int slot = k8 * 346 + ((2 * nf + kh) * 2 + p) * 17 + l15 + cidx;
        const half8 bh = Bh[slot], bl = Bl[slot];
#pragma unroll
        for (int m = 0; m < MF; ++m) {
          accM[m][nf] = __builtin_amdgcn_mfma_f32_16x16x32_f16(ah[cur][m], bh, accM[m][nf], 0, 0, 0);
          accX[m][nf] = __builtin_amdgcn_mfma_f32_16x16x32_f16(ah[cur][m], bl, accX[m][nf], 0, 0, 0);
          accX[m][nf] = __builtin_amdgcn_mfma_f32_16x16x32_f16(al[cur][m], bh, accX[m][nf], 0, 0, 0);
        }
      }
    }
  }
  // ---- epilogue: row = cout (k8*4+i), col = spatial (l15) ----
#pragma unroll
  for (int m = 0; m < MF; ++m)
#pragma unroll
    for (int nf = 0; nf < 4; ++nf) {
      int oy = oy0 + nf, ox = ox0 + l15;
#pragma unroll
      for (int i = 0; i < 4; ++i) {
        int co = cbase + m * 16 + k8 * 4 + i;
        float v = accM[m][nf][i] + accX[m][nf][i] * (1.0f / 2048.0f) + bias[co];
        if (RELU) v = fmaxf(v, 0.0f);
        out[(((size_t)b * COUT + co) * Hout + oy) * Wout + ox] = v;
      }
    }
}

// MFMA convT k4 s2 p1 (+ReLU), R6-verified. Parity decomposition.
template<int CIN, int RELU>
__global__ __launch_bounds__(256) void convT_mfma(
    const float* __restrict__ in, const _Float16* __restrict__ Whg,
    const _Float16* __restrict__ Wlg, const float* __restrict__ bias,
    float* __restrict__ out, int Cout, int Hin, int Win) {
  constexpr int NCB = CIN / 32;
  const int Hout = Hin * 2, Wout = Win * 2;
  const int TW = Win >> 4;
  __shared__ half8 Bh[4 * 72], Bl[4 * 72];
  const int tid = threadIdx.x;
  const int lane = tid & 63, w = tid >> 6;
  const int l15 = lane & 15, k8 = lane >> 4;
  const int tx = blockIdx.x % TW, ty = blockIdx.x / TW;
  const int cbo = blockIdx.y % (Cout >> 6);
  const int b   = blockIdx.y / (Cout >> 6);
  const int ty0 = ty << 1, tx0 = tx << 4;
  const int co0 = (cbo << 6) + (w << 4);
  const float* ip = in + (size_t)b * CIN * Hin * Win;
  const size_t HW = (size_t)Hin * Win;
  const size_t tapStride = (size_t)NCB * 4 * Cout * 8;

  f32x4 accM[4][2], accX[4][2];
#pragma unroll
  for (int p = 0; p < 4; ++p)
#pragma unroll
    for (int nf = 0; nf < 2; ++nf) {
      accM[p][nf] = f32x4{0,0,0,0};
      accX[p][nf] = f32x4{0,0,0,0};
    }

  for (int cb = 0; cb < NCB; ++cb) {
    __syncthreads();
    for (int u = tid; u < 288; u += 256) {
      int pos = u % 72, kk = u / 72;
      int r = pos / 18, c = pos - r * 18;
      int iy = ty0 - 1 + r, ix = tx0 - 1 + c;
      bool ok = (unsigned)iy < (unsigned)Hin && (unsigned)ix < (unsigned)Win;
      const float* gp = ip + ((size_t)cb * 32 + kk * 8) * HW + (ptrdiff_t)iy * Win + ix;
      half8 vh, vl;
#pragma unroll
      for (int j = 0; j < 8; ++j) {
        float x = ok ? gp[(size_t)j * HW] : 0.0f;
        _Float16 xh = (_Float16)x;
        vh[j] = xh; vl[j] = (_Float16)((x - (float)xh) * 2048.0f);
      }
      Bh[kk * 72 + pos] = vh;
      Bl[kk * 72 + pos] = vl;
    }
    __syncthreads();
    const _Float16* aph = Whg + (((size_t)cb * 4 + k8) * Cout + co0 + l15) * 8;
    const _Float16* apl = Wlg + (((size_t)cb * 4 + k8) * Cout + co0 + l15) * 8;
    half8 ahA = *(const half8*)(aph);
    half8 alA = *(const half8*)(apl);
#pragma unroll
    for (int t = 0; t < 16; ++t) {
      half8 ahN, alN;
      if (t < 15) {
        ahN = *(const half8*)(aph + (size_t)(t + 1) * tapStride);
        alN = *(const half8*)(apl + (size_t)(t + 1) * tapStride);
      }
      const int py = (t >> 3) & 1, px = (t >> 2) & 1;
      const int i0 = (t >> 1) & 1, i1 = t & 1;
      const int dy = py ? (i0 ? 0 : 1) : (i0 ? -1 : 0);
      const int dx = px ? (i1 ? 0 : 1) : (i1 ? -1 : 0);
      const int p = py * 2 + px;
#pragma unroll
      for (int nf = 0; nf < 2; ++nf) {
        int slot = k8 * 72 + (nf + 1 + dy) * 18 + (l15 + 1 + dx);
        half8 bh = Bh[slot], bl = Bl[slot];
        accM[p][nf] = __builtin_amdgcn_mfma_f32_16x16x32_f16(ahA, bh, accM[p][nf], 0, 0, 0);
        accX[p][nf] = __builtin_amdgcn_mfma_f32_16x16x32_f16(ahA, bl, accX[p][nf], 0, 0, 0);
        accX[p][nf] = __builtin_amdgcn_mfma_f32_16x16x32_f16(alA, bh, accX[p][nf], 0, 0, 0);
      }
      if (t < 15) { ahA = ahN; alA = alN; }
    }
  }
#pragma unroll
  for (int nf = 0; nf < 2; ++nf) {
#pragma unroll
    for (int i = 0; i < 4; ++i) {
      int co = co0 + k8 * 4 + i;
      float bb = bias[co];
#pragma unroll
      for (int py = 0; py < 2; ++py) {
        float v0 = accM[py * 2 + 0][nf][i] + accX[py * 2 + 0][nf][i] * (1.0f / 2048.0f) + bb;
        float v1 = accM[py * 2 + 1][nf][i] + accX[py * 2 + 1][nf][i] * (1.0f / 2048.0f) + bb;
        if (RELU) { v0 = fmaxf(v0, 0.0f); v1 = fmaxf(v1, 0.0f); }
        int oy = 2 * (ty0 + nf) + py, ox = 2 * (tx0 + l15);
        *(float2*)(out + (((size_t)b * Cout + co) * Hout + oy) * Wout + ox) =
            make_float2(v0, v1);
      }
    }
  }
}

// ---------------- f32 kernels (R3-verified, unchanged) ---------------------

template<int CIN, int G, int RELU>
__global__ __launch_bounds__(256) void conv_t(
    const float* __restrict__ in, const float* __restrict__ wt,
    const float* __restrict__ bias, float* __restrict__ out,
    int Cout, int Hin, int Win) {
  const int Hout = Hin >> 1, Wout = Win >> 1;
  const int TW = Wout >> 4;
  __shared__ float tile[34 * 35];
  int tid = threadIdx.x;
  int oxl = tid & 15, oyl = tid >> 4;
  int tyt = blockIdx.x / TW, txt = blockIdx.x - tyt * TW;
  int oy0 = tyt << 4, ox0 = txt << 4;
  int cg = blockIdx.y % (Cout / G);
  int b  = blockIdx.y / (Cout / G);
  int co0 = cg * G;
  const int iy_org = 2 * oy0 - 1, ix_org = 2 * ox0 - 1;
  const float* ip = in + (size_t)b * CIN * Hin * Win;
  float acc[G];
#pragma unroll
  for (int j = 0; j < G; ++j) acc[j] = bias[co0 + j];
  const int lbase = (2 * oyl) * 35 + 2 * oxl;
  for (int ci = 0; ci < CIN; ++ci) {
    const float* ic = ip + (size_t)ci * Hin * Win;
    __syncthreads();
#pragma unroll
    for (int k = 0; k < 5; ++k) {
      int idx = tid + k * 256;
      if (idx < 34 * 34) {
        int r = idx / 34, c = idx - r * 34;
        int iy = iy_org + r, ix = ix_org + c;
        float v = ((unsigned)iy < (unsigned)Hin && (unsigned)ix < (unsigned)Win)
                      ? ic[(size_t)iy * Win + ix] : 0.0f;
        tile[r * 35 + c] = v;
      }
    }
    __syncthreads();
    float xv[16];
#pragma unroll
    for (int kh = 0; kh < 4; ++kh)
#pragma unroll
      for (int kw = 0; kw < 4; ++kw)
        xv[kh * 4 + kw] = tile[lbase + kh * 35 + kw];
    const float* wc = wt + ((size_t)co0 * CIN + ci) * 16;
#pragma unroll
    for (int j = 0; j < G; ++j) {
      const float* wj = wc + (size_t)j * CIN * 16;
#pragma unroll
      for (int t2 = 0; t2 < 16; ++t2) acc[j] = fmaf(xv[t2], wj[t2], acc[j]);
    }
  }
  size_t cs = (size_t)Hout * Wout;
  float* op = out + ((size_t)(b * Cout + co0) * Hout + (oy0 + oyl)) * Wout + ox0 + oxl;
#pragma unroll
  for (int j = 0; j < G; ++j) {
    float v = acc[j];
    if (RELU) v = fmaxf(v, 0.0f);
    op[(size_t)j * cs] = v;
  }
}

template<int CIN, int G>
__global__ __launch_bounds__(256) void conv1x1_k(
    const float* __restrict__ in, const float* __restrict__ wt,
    const float* __restrict__ bias, float* __restrict__ out,
    int Cout, int HW) {
  int hw = blockIdx.x * 256 + threadIdx.x;
  int cg = blockIdx.y % (Cout / G);
  int b  = blockIdx.y / (Cout / G);
  int co0 = cg * G;
  const float* ip = in + (size_t)b * CIN * HW + hw;
  float acc[G];
#pragma unroll
  for (int j = 0; j < G; ++j) acc[j] = bias[co0 + j];
#pragma unroll 4
  for (int ci = 0; ci < CIN; ++ci) {
    float xv = ip[(size_t)ci * HW];
#pragma unroll
    for (int j = 0; j < G; ++j)
      acc[j] = fmaf(xv, wt[(size_t)(co0 + j) * CIN + ci], acc[j]);
  }
  float* op = out + ((size_t)(b * Cout + co0)) * HW + hw;
#pragma unroll
  for (int j = 0; j < G; ++j) op[(size_t)j * HW] = acc[j];
}

__global__ __launch_bounds__(128) void vq_k(
    const float* __restrict__ ze, const float* __restrict__ emb,
    float* __restrict__ zq, float* __restrict__ partial) {
  __shared__ float4 se4[128 * 16];
  __shared__ float red[128];
  int tid = threadIdx.x;
  int gid = blockIdx.x * 128 + tid;
  int b = gid >> 10, n = gid & 1023;
  const float* zp = ze + ((size_t)b << 16) + n;
  float4 v4[16];
#pragma unroll
  for (int d = 0; d < 16; ++d) {
    v4[d].x = zp[(size_t)(4 * d + 0) << 10];
    v4[d].y = zp[(size_t)(4 * d + 1) << 10];
    v4[d].z = zp[(size_t)(4 * d + 2) << 10];
    v4[d].w = zp[(size_t)(4 * d + 3) << 10];
  }
  float best = 1e30f; int bi = 0;
  for (int c = 0; c < 4; ++c) {
    __syncthreads();
    for (int i = tid; i < 2048; i += 128)
      se4[i] = ((const float4*)emb)[(c << 11) + i];
    __syncthreads();
    for (int k = 0; k < 128; ++k) {
      const float4* e = se4 + (k << 4);
      float s = 0.0f;
#pragma unroll
      for (int d = 0; d < 16; ++d) {
        float4 ev = e[d];
        float t0 = v4[d].x - ev.x; s = fmaf(t0, t0, s);
        float t1 = v4[d].y - ev.y; s = fmaf(t1, t1, s);
        float t2 = v4[d].z - ev.z; s = fmaf(t2, t2, s);
        float t3 = v4[d].w - ev.w; s = fmaf(t3, t3, s);
      }
      if (s < best) { best = s; bi = (c << 7) + k; }
    }
  }
  const float4* eb4 = (const float4*)emb + ((size_t)bi << 4);
  float* qp = zq + ((size_t)b << 16) + n;
  float ls = 0.0f;
#pragma unroll
  for (int d = 0; d < 16; ++d) {
    float4 q = eb4[d];
    qp[(size_t)(4 * d + 0) << 10] = q.x;
    qp[(size_t)(4 * d + 1) << 10] = q.y;
    qp[(size_t)(4 * d + 2) << 10] = q.z;
    qp[(size_t)(4 * d + 3) << 10] = q.w;
    float t0 = q.x - v4[d].x; ls = fmaf(t0, t0, ls);
    float t1 = q.y - v4[d].y; ls = fmaf(t1, t1, ls);
    float t2 = q.z - v4[d].z; ls = fmaf(t2, t2, ls);
    float t3 = q.w - v4[d].w; ls = fmaf(t3, t3, ls);
  }
  red[tid] = ls;
  __syncthreads();
  for (int s = 64; s > 0; s >>= 1) {
    if (tid < s) red[tid] += red[tid + s];
    __syncthreads();
  }
  if (tid == 0) partial[blockIdx.x] = red[0];
}

__global__ __launch_bounds__(256) void loss_fin(
    const float* __restrict__ partial, float* __restrict__ out) {
  __shared__ float red[256];
  int t = threadIdx.x;
  red[t] = partial[t];
  __syncthreads();
  for (int s = 128; s > 0; s >>= 1) {
    if (t < s) red[t] += red[t + s];
    __syncthreads();
  }
  if (t == 0) out[0] = red[0] * (2.0f / 2097152.0f);
}

template<int CIN, int G, int ACT>
__global__ __launch_bounds__(256) void convT_t(
    const float* __restrict__ in, const float* __restrict__ wt,
    const float* __restrict__ bias, float* __restrict__ out,
    int Cout, int Hin, int Win) {
  const int Hout = Hin * 2, Wout = Win * 2;
  const int TW = Win >> 4;
  __shared__ float tile[18 * 19];
  int tid = threadIdx.x;
  int txl = tid & 15, tyl = tid >> 4;
  int tyt = blockIdx.x / TW, txt = blockIdx.x - tyt * TW;
  int ty0 = tyt << 4, tx0 = txt << 4;
  int og = blockIdx.y % (Cout / G);
  int b  = blockIdx.y / (Cout / G);
  int o0 = og * G;
  const int iy_org = ty0 - 1, ix_org = tx0 - 1;
  const float* ip = in + (size_t)b * CIN * Hin * Win;
  float a00[G], a01[G], a10[G], a11[G];
#pragma unroll
  for (int j = 0; j < G; ++j) {
    float bb = bias[o0 + j];
    a00[j] = bb; a01[j] = bb; a10[j] = bb; a11[j] = bb;
  }
  const int lb = tyl * 19 + txl;
  for (int i = 0; i < CIN; ++i) {
    const float* ic = ip + (size_t)i * Hin * Win;
    __syncthreads();
#pragma unroll
    for (int k = 0; k < 2; ++k) {
      int idx = tid + k * 256;
      if (idx < 18 * 18) {
        int r = idx / 18, c = idx - r * 18;
        int iy = iy_org + r, ix = ix_org + c;
        float v = ((unsigned)iy < (unsigned)Hin && (unsigned)ix < (unsigned)Win)
                      ? ic[(size_t)iy * Win + ix] : 0.0f;
        tile[r * 19 + c] = v;
      }
    }
    __syncthreads();
    float x00 = tile[lb],          x01 = tile[lb + 1],      x02 = tile[lb + 2];
    float x10 = tile[lb + 19],     x11 = tile[lb + 20],     x12 = tile[lb + 21];
    float x20 = tile[lb + 38],     x21 = tile[lb + 39],     x22 = tile[lb + 40];
    const float* wv = wt + ((size_t)i * Cout + o0) * 16;
#pragma unroll
    for (int j = 0; j < G; ++j) {
      const float* w4 = wv + j * 16;
      a00[j] = fmaf(x11, w4[5],  fmaf(x10, w4[7],  fmaf(x01, w4[13], fmaf(x00, w4[15], a00[j]))));
      a01[j] = fmaf(x12, w4[4],  fmaf(x11, w4[6],  fmaf(x02, w4[12], fmaf(x01, w4[14], a01[j]))));
      a10[j] = fmaf(x21, w4[1],  fmaf(x20, w4[3],  fmaf(x11, w4[9],  fmaf(x10, w4[11], a10[j]))));
      a11[j] = fmaf(x22, w4[0],  fmaf(x21, w4[2],  fmaf(x12, w4[8],  fmaf(x11, w4[10], a11[j]))));
    }
  }
  size_t cs = (size_t)Hout * Wout;
  int ty = ty0 + tyl, tx = tx0 + txl;
  size_t base = ((size_t)(b * Cout + o0) * Hout + 2 * (size_t)ty) * Wout + 2 * tx;
#pragma unroll
  for (int j = 0; j < G; ++j) {
    float v00 = a00[j], v01 = a01[j], v10 = a10[j], v11 = a11[j];
    if (ACT == 1) {
      v00 = fmaxf(v00, 0.0f); v01 = fmaxf(v01, 0.0f);
      v10 = fmaxf(v10, 0.0f); v11 = fmaxf(v11, 0.0f);
    } else if (ACT == 2) {
      v00 = 1.0f / (1.0f + expf(-v00)); v01 = 1.0f / (1.0f + expf(-v01));
      v10 = 1.0f / (1.0f + expf(-v10)); v11 = 1.0f / (1.0f + expf(-v11));
    }
    *(float2*)(out + base + (size_t)j * cs)        = make_float2(v00, v01);
    *(float2*)(out + base + (size_t)j * cs + Wout) = make_float2(v10, v11);
  }
}

extern "C" void kernel_launch(void* const* d_in, const int* in_sizes, int n_in,
                              void* d_out, int out_size, void* d_ws, size_t ws_size,
                              hipStream_t stream) {
  const float* x   = (const float*)d_in[0];
  const float* ew1 = (const float*)d_in[1];
  const float* eb1 = (const float*)d_in[2];
  const float* ew2 = (const float*)d_in[3];
  const float* eb2 = (const float*)d_in[4];
  const float* ew3 = (const float*)d_in[5];
  const float* eb3 = (const float*)d_in[6];
  const float* pw  = (const float*)d_in[7];
  const float* pb  = (const float*)d_in[8];
  const float* emb = (const float*)d_in[9];
  const float* dw1 = (const float*)d_in[10];
  const float* db1 = (const float*)d_in[11];
  const float* dw2 = (const float*)d_in[12];
  const float* db2 = (const float*)d_in[13];
  const float* dw3 = (const float*)d_in[14];
  const float* db3 = (const float*)d_in[15];
  float* out = (float*)d_out;
  char* ws = (char*)d_ws;

  const size_t PER  = 13107200ull;
  const size_t WEXT = 4096ull + 13631488ull;
  int CB = 32;
  while (CB > 1 && (size_t)CB * PER + WEXT > ws_size) CB >>= 1;
  const size_t SA = (size_t)CB * 8388608ull;
  const size_t SB = (size_t)CB * 4194304ull;
  const size_t SC = (size_t)CB * 262144ull;
  float* A    = (float*)(ws);
  float* Bp   = (float*)(ws + SA);
  float* ze   = (float*)(ws + SA + SB);
  float* zq   = (float*)(ws + SA + SB + SC);
  float* part = (float*)(ws + SA + SB + 2 * SC);           // 256 floats
  _Float16* wh2  = (_Float16*)(ws + SA + SB + 2 * SC + 4096);
  _Float16* wl2  = wh2 + 524288;    // conv2: 256*128*16
  _Float16* wh3  = wl2 + 524288;
  _Float16* wl3  = wh3 + 2097152;   // conv3: 512*256*16
  _Float16* whT1 = wl3 + 2097152;
  _Float16* wlT1 = whT1 + 262144;   // convT1: 64*256*16
  _Float16* whT2 = wlT1 + 262144;
  _Float16* wlT2 = whT2 + 524288;   // convT2: 256*128*16

  wsplit_k<128><<<128, 256, 0, stream>>>(ew2, wh2, wl2, 256);
  wsplit_k<256><<<512, 256, 0, stream>>>(ew3, wh3, wl3, 512);
  wsplitT_k<64><<<64,  256, 0, stream>>>(dw1, whT1, wlT1, 256);
  wsplitT_k<256><<<128, 256, 0, stream>>>(dw2, whT2, wlT2, 128);

  for (int c0 = 0; c0 < 32; c0 += CB) {
    const float* xc = x + (size_t)c0 * 3 * 65536;
    float* outc = out + (size_t)c0 * 3 * 65536;
    // encoder
    conv_t<3, 16, 1><<<dim3(64, CB * 8), 256, 0, stream>>>(xc, ew1, eb1, A, 128, 256, 256);
    conv_mfma2<128, 256, 1, 1><<<dim3(64, CB),     256, 0, stream>>>(A,  wh2, wl2, eb2, Bp, 128, 128);
    conv_mfma2<256, 512, 2, 1><<<dim3(16, CB * 2), 256, 0, stream>>>(Bp, wh3, wl3, eb3, A,  64,  64);
    conv1x1_k<512, 4><<<dim3(4, CB * 16), 256, 0, stream>>>(A, pw, pb, ze, 64, 1024);
    // VQ
    vq_k<<<CB * 8, 128, 0, stream>>>(ze, emb, zq, part + (size_t)c0 * 8);
    // decoder
    convT_mfma<64,  1><<<dim3(32,  CB * 4), 256, 0, stream>>>(zq, whT1, wlT1, db1, Bp, 256, 32, 32);
    convT_mfma<256, 1><<<dim3(128, CB * 2), 256, 0, stream>>>(Bp, whT2, wlT2, db2, A, 128, 64, 64);
    convT_t<128, 3, 2><<<dim3(64, CB * 1), 256, 0, stream>>>(A, dw3, db3, outc, 3, 128, 128);
  }
  loss_fin<<<1, 256, 0, stream>>>(part, out + (size_t)(out_size - 1));
}

// Round 8
// 2340.989 us; speedup vs baseline: 10.2507x; 1.0990x over previous
//
#include <hip/hip_runtime.h>
#include <cstddef>

typedef __attribute__((ext_vector_type(8))) _Float16 half8;
typedef __attribute__((ext_vector_type(4))) float f32x4;

static __device__ __forceinline__ unsigned packhl(float v) {
  _Float16 h = (_Float16)v;
  _Float16 l = (_Float16)((v - (float)h) * 2048.0f);
  return (unsigned)__builtin_bit_cast(unsigned short, h) |
         ((unsigned)__builtin_bit_cast(unsigned short, l) << 16);
}

// ---------------------------------------------------------------------------
// VQ-VAE forward. MFMA f16 2-term-split tap-GEMM for conv2/conv3/convT1/convT2.
// Activations at MFMA-consumer boundaries stored PACKED: u32=(h|l<<16) in
// 8-channel-blocked layout [c8][y][x][j] (same byte size as f32).
// Math order identical to R5-R7 (bit-identical outputs).
// ---------------------------------------------------------------------------

// Pre-split conv weights: W[Cout][CIN][4][4] -> [tap][cb][k8][cout][8] f16 h/l
template<int CIN>
__global__ __launch_bounds__(256) void wsplit_k(
    const float* __restrict__ W, _Float16* __restrict__ Wh,
    _Float16* __restrict__ Wl, int Cout) {
  constexpr int NCB = CIN / 32;
  int idx = blockIdx.x * 256 + threadIdx.x;
  if (idx >= Cout * CIN) return;
  int ci = idx % CIN, co = idx / CIN;
  int cb = ci >> 5, k8 = (ci >> 3) & 3, j = ci & 7;
  const float* wp = W + (size_t)idx * 16;
#pragma unroll
  for (int tap = 0; tap < 16; ++tap) {
    float w = wp[tap];
    _Float16 wh = (_Float16)w;
    _Float16 wl = (_Float16)((w - (float)wh) * 2048.0f);
    size_t o = (((size_t)(tap * NCB + cb) * 4 + k8) * Cout + co) * 8 + j;
    Wh[o] = wh; Wl[o] = wl;
  }
}

// Pre-split convT weights: W[CIN][Cout][4][4] -> [t][cb][k8][cout][8] f16 h/l
template<int CIN>
__global__ __launch_bounds__(256) void wsplitT_k(
    const float* __restrict__ W, _Float16* __restrict__ Wh,
    _Float16* __restrict__ Wl, int Cout) {
  constexpr int NCB = CIN / 32;
  int idx = blockIdx.x * 256 + threadIdx.x;
  if (idx >= CIN * Cout) return;
  int co = idx % Cout, ci = idx / Cout;
  int cb = ci >> 5, k8 = (ci >> 3) & 3, j = ci & 7;
  const float* wp = W + (size_t)idx * 16;
#pragma unroll
  for (int t = 0; t < 16; ++t) {
    int py = (t >> 3) & 1, px = (t >> 2) & 1, i0 = (t >> 1) & 1, i1 = t & 1;
    int kh = py ? (i0 ? 2 : 0) : (i0 ? 3 : 1);
    int kw = px ? (i1 ? 2 : 0) : (i1 ? 3 : 1);
    float w = wp[kh * 4 + kw];
    _Float16 wh = (_Float16)w;
    _Float16 wl = (_Float16)((w - (float)wh) * 2048.0f);
    size_t o = (((size_t)(t * NCB + cb) * 4 + k8) * Cout + co) * 8 + j;
    Wh[o] = wh; Wl[o] = wl;
  }
}

// MFMA conv k4 s2 p1 (+ReLU). NF out-rows x 16 cols per block, all COUT/CGRP
// couts. Packed-u32 input (8ch-blocked); optional packed output.
template<int CIN, int COUT, int CGRP, int NF, int RELU, int PACKOUT>
__global__ __launch_bounds__(256) void conv_mfma2(
    const unsigned* __restrict__ inU, const _Float16* __restrict__ Whg,
    const _Float16* __restrict__ Wlg, const float* __restrict__ bias,
    float* __restrict__ out, int Hin, int Win) {
  constexpr int NCB  = CIN / 32;
  constexpr int MT   = COUT / CGRP;
  constexpr int MF   = MT / 64;
  constexpr int ROWS = 2 * NF + 2;
  constexpr int NPOS = ROWS * 34;
  constexpr int K8S  = NPOS + 6;          // +6 half8 -> 8-bank k8 stagger
  const int Hout = Hin >> 1, Wout = Win >> 1;
  const int TW = Wout >> 4;
  __shared__ half8 Bh[4 * K8S], Bl[4 * K8S];
  const int tid = threadIdx.x;
  const int lane = tid & 63, w = tid >> 6;
  const int l15 = lane & 15, k8 = lane >> 4;
  const int tx = blockIdx.x % TW, ty = blockIdx.x / TW;
  const int cg = blockIdx.y % CGRP;
  const int b  = blockIdx.y / CGRP;
  const int oy0 = ty * NF, ox0 = tx << 4;
  const int iy_org = 2 * oy0 - 1, ix_org = 2 * ox0 - 1;
  const int cbase = cg * MT + w * (MT / 4);
  const size_t HW = (size_t)Hin * Win;
  const size_t tapStride = (size_t)NCB * 4 * COUT * 8;

  f32x4 accM[MF][NF], accX[MF][NF];
#pragma unroll
  for (int m = 0; m < MF; ++m)
#pragma unroll
    for (int nf = 0; nf < NF; ++nf) {
      accM[m][nf] = f32x4{0,0,0,0};
      accX[m][nf] = f32x4{0,0,0,0};
    }

  for (int cb = 0; cb < NCB; ++cb) {
    __syncthreads();
    // ---- stage B from packed u32 (2x uint4 per (pos,k8)) ----
    for (int u = tid; u < NPOS * 4; u += 256) {
      int kk = u / NPOS, pos = u - kk * NPOS;
      int hy = pos / 34, hx = pos - hy * 34;
      int iy = iy_org + hy, ix = ix_org + hx;
      bool ok = (unsigned)iy < (unsigned)Hin && (unsigned)ix < (unsigned)Win;
      uint4 qa = {0,0,0,0}, qb = {0,0,0,0};
      if (ok) {
        const uint4* gp = (const uint4*)(inU +
            (((size_t)b * (CIN / 8) + cb * 4 + kk) * HW + (size_t)iy * Win + ix) * 8);
        qa = gp[0]; qb = gp[1];
      }
      unsigned av[8] = {qa.x, qa.y, qa.z, qa.w, qb.x, qb.y, qb.z, qb.w};
      half8 vh, vl;
#pragma unroll
      for (int j = 0; j < 8; ++j) {
        vh[j] = __builtin_bit_cast(_Float16, (unsigned short)(av[j] & 0xffffu));
        vl[j] = __builtin_bit_cast(_Float16, (unsigned short)(av[j] >> 16));
      }
      int slotBase = (hy * 2 + (hx & 1)) * 17 + (hx >> 1);
      Bh[kk * K8S + slotBase] = vh;
      Bl[kk * K8S + slotBase] = vl;
    }
    __syncthreads();
    // ---- 16 taps; A-frags 2-deep register pipeline ----
    const _Float16* aph = Whg + (((size_t)cb * 4 + k8) * COUT + cbase + l15) * 8;
    const _Float16* apl = Wlg + (((size_t)cb * 4 + k8) * COUT + cbase + l15) * 8;
    half8 ah[2][MF], al[2][MF];
#pragma unroll
    for (int m = 0; m < MF; ++m) {
      ah[0][m] = *(const half8*)(aph + m * 128);
      al[0][m] = *(const half8*)(apl + m * 128);
    }
#pragma unroll
    for (int tp = 0; tp < 16; ++tp) {
      const int cur = tp & 1, nxt = cur ^ 1;
      if (tp < 15) {
#pragma unroll
        for (int m = 0; m < MF; ++m) {
          ah[nxt][m] = *(const half8*)(aph + (size_t)(tp + 1) * tapStride + m * 128);
          al[nxt][m] = *(const half8*)(apl + (size_t)(tp + 1) * tapStride + m * 128);
        }
      }
      const int kh = tp >> 2, kw = tp & 3;
      const int p = kw & 1, cidx = kw >> 1;
#pragma unroll
      for (int nf = 0; nf < NF; ++nf) {
        const int slot = k8 * K8S + ((2 * nf + kh) * 2 + p) * 17 + l15 + cidx;
        const half8 bh = Bh[slot], bl = Bl[slot];
#pragma unroll
        for (int m = 0; m < MF; ++m) {
          accM[m][nf] = __builtin_amdgcn_mfma_f32_16x16x32_f16(ah[cur][m], bh, accM[m][nf], 0, 0, 0);
          accX[m][nf] = __builtin_amdgcn_mfma_f32_16x16x32_f16(ah[cur][m], bl, accX[m][nf], 0, 0, 0);
          accX[m][nf] = __builtin_amdgcn_mfma_f32_16x16x32_f16(al[cur][m], bh, accX[m][nf], 0, 0, 0);
        }
      }
    }
  }
  // ---- epilogue ----
#pragma unroll
  for (int m = 0; m < MF; ++m)
#pragma unroll
    for (int nf = 0; nf < NF; ++nf) {
      int oy = oy0 + nf, ox = ox0 + l15;
      if (PACKOUT) {
        unsigned pk[4];
#pragma unroll
        for (int i = 0; i < 4; ++i) {
          int co = cbase + m * 16 + k8 * 4 + i;
          float v = accM[m][nf][i] + accX[m][nf][i] * (1.0f / 2048.0f) + bias[co];
          if (RELU) v = fmaxf(v, 0.0f);
          pk[i] = packhl(v);
        }
        int co8 = (cbase + m * 16 + k8 * 4) >> 3;
        int j0 = (k8 & 1) * 4;
        unsigned* outU = (unsigned*)out;
        *(uint4*)(outU + (((size_t)b * (COUT / 8) + co8) * ((size_t)Hout * Wout)
                          + (size_t)oy * Wout + ox) * 8 + j0) =
            make_uint4(pk[0], pk[1], pk[2], pk[3]);
      } else {
#pragma unroll
        for (int i = 0; i < 4; ++i) {
          int co = cbase + m * 16 + k8 * 4 + i;
          float v = accM[m][nf][i] + accX[m][nf][i] * (1.0f / 2048.0f) + bias[co];
          if (RELU) v = fmaxf(v, 0.0f);
          out[(((size_t)b * COUT + co) * Hout + oy) * Wout + ox] = v;
        }
      }
    }
}

// MFMA convT k4 s2 p1 (+ReLU). Parity decomposition (R6-verified).
// PACKIN: packed-u32 input; PACKOUT: packed-u32 output.
template<int CIN, int RELU, int PACKIN, int PACKOUT>
__global__ __launch_bounds__(256) void convT_mfma(
    const float* __restrict__ in, const _Float16* __restrict__ Whg,
    const _Float16* __restrict__ Wlg, const float* __restrict__ bias,
    float* __restrict__ out, int Cout, int Hin, int Win) {
  constexpr int NCB = CIN / 32;
  const int Hout = Hin * 2, Wout = Win * 2;
  const int TW = Win >> 4;
  __shared__ half8 Bh[4 * 72], Bl[4 * 72];
  const int tid = threadIdx.x;
  const int lane = tid & 63, w = tid >> 6;
  const int l15 = lane & 15, k8 = lane >> 4;
  const int tx = blockIdx.x % TW, ty = blockIdx.x / TW;
  const int cbo = blockIdx.y % (Cout >> 6);
  const int b   = blockIdx.y / (Cout >> 6);
  const int ty0 = ty << 1, tx0 = tx << 4;
  const int co0 = (cbo << 6) + (w << 4);
  const size_t HW = (size_t)Hin * Win;
  const size_t tapStride = (size_t)NCB * 4 * Cout * 8;

  f32x4 accM[4][2], accX[4][2];
#pragma unroll
  for (int p = 0; p < 4; ++p)
#pragma unroll
    for (int nf = 0; nf < 2; ++nf) {
      accM[p][nf] = f32x4{0,0,0,0};
      accX[p][nf] = f32x4{0,0,0,0};
    }

  for (int cb = 0; cb < NCB; ++cb) {
    __syncthreads();
    for (int u = tid; u < 288; u += 256) {
      int pos = u % 72, kk = u / 72;
      int r = pos / 18, c = pos - r * 18;
      int iy = ty0 - 1 + r, ix = tx0 - 1 + c;
      bool ok = (unsigned)iy < (unsigned)Hin && (unsigned)ix < (unsigned)Win;
      half8 vh, vl;
      if (PACKIN) {
        uint4 qa = {0,0,0,0}, qb = {0,0,0,0};
        if (ok) {
          const uint4* gp = (const uint4*)((const unsigned*)in +
              (((size_t)b * (CIN / 8) + cb * 4 + kk) * HW + (size_t)iy * Win + ix) * 8);
          qa = gp[0]; qb = gp[1];
        }
        unsigned av[8] = {qa.x, qa.y, qa.z, qa.w, qb.x, qb.y, qb.z, qb.w};
#pragma unroll
        for (int j = 0; j < 8; ++j) {
          vh[j] = __builtin_bit_cast(_Float16, (unsigned short)(av[j] & 0xffffu));
          vl[j] = __builtin_bit_cast(_Float16, (unsigned short)(av[j] >> 16));
        }
      } else {
        const float* gp = in + ((size_t)b * CIN + cb * 32 + kk * 8) * HW
                          + (ptrdiff_t)iy * Win + ix;
#pragma unroll
        for (int j = 0; j < 8; ++j) {
          float x = ok ? gp[(size_t)j * HW] : 0.0f;
          _Float16 xh = (_Float16)x;
          vh[j] = xh; vl[j] = (_Float16)((x - (float)xh) * 2048.0f);
        }
      }
      Bh[kk * 72 + pos] = vh;
      Bl[kk * 72 + pos] = vl;
    }
    __syncthreads();
    const _Float16* aph = Whg + (((size_t)cb * 4 + k8) * Cout + co0 + l15) * 8;
    const _Float16* apl = Wlg + (((size_t)cb * 4 + k8) * Cout + co0 + l15) * 8;
    half8 ahA = *(const half8*)(aph);
    half8 alA = *(const half8*)(apl);
#pragma unroll
    for (int t = 0; t < 16; ++t) {
      half8 ahN, alN;
      if (t < 15) {
        ahN = *(const half8*)(aph + (size_t)(t + 1) * tapStride);
        alN = *(const half8*)(apl + (size_t)(t + 1) * tapStride);
      }
      const int py = (t >> 3) & 1, px = (t >> 2) & 1;
      const int i0 = (t >> 1) & 1, i1 = t & 1;
      const int dy = py ? (i0 ? 0 : 1) : (i0 ? -1 : 0);
      const int dx = px ? (i1 ? 0 : 1) : (i1 ? -1 : 0);
      const int p = py * 2 + px;
#pragma unroll
      for (int nf = 0; nf < 2; ++nf) {
        int slot = k8 * 72 + (nf + 1 + dy) * 18 + (l15 + 1 + dx);
        half8 bh = Bh[slot], bl = Bl[slot];
        accM[p][nf] = __builtin_amdgcn_mfma_f32_16x16x32_f16(ahA, bh, accM[p][nf], 0, 0, 0);
        accX[p][nf] = __builtin_amdgcn_mfma_f32_16x16x32_f16(ahA, bl, accX[p][nf], 0, 0, 0);
        accX[p][nf] = __builtin_amdgcn_mfma_f32_16x16x32_f16(alA, bh, accX[p][nf], 0, 0, 0);
      }
      if (t < 15) { ahA = ahN; alA = alN; }
    }
  }
#pragma unroll
  for (int nf = 0; nf < 2; ++nf) {
#pragma unroll
    for (int i = 0; i < 4; ++i) {
      int co = co0 + k8 * 4 + i;
      float bb = bias[co];
#pragma unroll
      for (int py = 0; py < 2; ++py) {
        float v0 = accM[py * 2 + 0][nf][i] + accX[py * 2 + 0][nf][i] * (1.0f / 2048.0f) + bb;
        float v1 = accM[py * 2 + 1][nf][i] + accX[py * 2 + 1][nf][i] * (1.0f / 2048.0f) + bb;
        if (RELU) { v0 = fmaxf(v0, 0.0f); v1 = fmaxf(v1, 0.0f); }
        int oy = 2 * (ty0 + nf) + py, ox = 2 * (tx0 + l15);
        if (PACKOUT) {
          unsigned* outU = (unsigned*)out;
          int co8 = (co0 >> 3) + (k8 >> 1);
          int j = (k8 * 4 + i) & 7;
          size_t base = ((size_t)b * (Cout / 8) + co8) * ((size_t)Hout * Wout);
          outU[(base + (size_t)oy * Wout + ox) * 8 + j]     = packhl(v0);
          outU[(base + (size_t)oy * Wout + ox + 1) * 8 + j] = packhl(v1);
        } else {
          *(float2*)(out + (((size_t)b * Cout + co) * Hout + oy) * Wout + ox) =
              make_float2(v0, v1);
        }
      }
    }
  }
}

// ---------------- f32 kernels ----------------------------------------------

// Conv2d k4 s2 p1 f32 (+ReLU); PACKOUT writes packed u32 8ch-blocked.
template<int CIN, int G, int RELU, int PACKOUT>
__global__ __launch_bounds__(256) void conv_t(
    const float* __restrict__ in, const float* __restrict__ wt,
    const float* __restrict__ bias, float* __restrict__ out,
    int Cout, int Hin, int Win) {
  const int Hout = Hin >> 1, Wout = Win >> 1;
  const int TW = Wout >> 4;
  __shared__ float tile[34 * 35];
  int tid = threadIdx.x;
  int oxl = tid & 15, oyl = tid >> 4;
  int tyt = blockIdx.x / TW, txt = blockIdx.x - tyt * TW;
  int oy0 = tyt << 4, ox0 = txt << 4;
  int cg = blockIdx.y % (Cout / G);
  int b  = blockIdx.y / (Cout / G);
  int co0 = cg * G;
  const int iy_org = 2 * oy0 - 1, ix_org = 2 * ox0 - 1;
  const float* ip = in + (size_t)b * CIN * Hin * Win;
  float acc[G];
#pragma unroll
  for (int j = 0; j < G; ++j) acc[j] = bias[co0 + j];
  const int lbase = (2 * oyl) * 35 + 2 * oxl;
  for (int ci = 0; ci < CIN; ++ci) {
    const float* ic = ip + (size_t)ci * Hin * Win;
    __syncthreads();
#pragma unroll
    for (int k = 0; k < 5; ++k) {
      int idx = tid + k * 256;
      if (idx < 34 * 34) {
        int r = idx / 34, c = idx - r * 34;
        int iy = iy_org + r, ix = ix_org + c;
        float v = ((unsigned)iy < (unsigned)Hin && (unsigned)ix < (unsigned)Win)
                      ? ic[(size_t)iy * Win + ix] : 0.0f;
        tile[r * 35 + c] = v;
      }
    }
    __syncthreads();
    float xv[16];
#pragma unroll
    for (int kh = 0; kh < 4; ++kh)
#pragma unroll
      for (int kw = 0; kw < 4; ++kw)
        xv[kh * 4 + kw] = tile[lbase + kh * 35 + kw];
    const float* wc = wt + ((size_t)co0 * CIN + ci) * 16;
#pragma unroll
    for (int j = 0; j < G; ++j) {
      const float* wj = wc + (size_t)j * CIN * 16;
#pragma unroll
      for (int t2 = 0; t2 < 16; ++t2) acc[j] = fmaf(xv[t2], wj[t2], acc[j]);
    }
  }
  int oy = oy0 + oyl, ox = ox0 + oxl;
  if (RELU) {
#pragma unroll
    for (int j = 0; j < G; ++j) acc[j] = fmaxf(acc[j], 0.0f);
  }
  if (PACKOUT) {
    unsigned* outU = (unsigned*)out;
    size_t cs = (size_t)Hout * Wout;
#pragma unroll
    for (int mb = 0; mb < G / 8; ++mb) {
      unsigned pk[8];
#pragma unroll
      for (int j = 0; j < 8; ++j) pk[j] = packhl(acc[mb * 8 + j]);
      size_t base = (((size_t)b * (Cout / 8) + (co0 >> 3) + mb) * cs
                     + (size_t)oy * Wout + ox) * 8;
      *(uint4*)(outU + base)     = make_uint4(pk[0], pk[1], pk[2], pk[3]);
      *(uint4*)(outU + base + 4) = make_uint4(pk[4], pk[5], pk[6], pk[7]);
    }
  } else {
    size_t cs = (size_t)Hout * Wout;
    float* op = out + ((size_t)(b * Cout + co0) * Hout + oy) * Wout + ox;
#pragma unroll
    for (int j = 0; j < G; ++j) op[(size_t)j * cs] = acc[j];
  }
}

template<int CIN, int G>
__global__ __launch_bounds__(256) void conv1x1_k(
    const float* __restrict__ in, const float* __restrict__ wt,
    const float* __restrict__ bias, float* __restrict__ out,
    int Cout, int HW) {
  int hw = blockIdx.x * 256 + threadIdx.x;
  int cg = blockIdx.y % (Cout / G);
  int b  = blockIdx.y / (Cout / G);
  int co0 = cg * G;
  const float* ip = in + (size_t)b * CIN * HW + hw;
  float acc[G];
#pragma unroll
  for (int j = 0; j < G; ++j) acc[j] = bias[co0 + j];
#pragma unroll 4
  for (int ci = 0; ci < CIN; ++ci) {
    float xv = ip[(size_t)ci * HW];
#pragma unroll
    for (int j = 0; j < G; ++j)
      acc[j] = fmaf(xv, wt[(size_t)(co0 + j) * CIN + ci], acc[j]);
  }
  float* op = out + ((size_t)(b * Cout + co0)) * HW + hw;
#pragma unroll
  for (int j = 0; j < G; ++j) op[(size_t)j * HW] = acc[j];
}

__global__ __launch_bounds__(128) void vq_k(
    const float* __restrict__ ze, const float* __restrict__ emb,
    float* __restrict__ zq, float* __restrict__ partial) {
  __shared__ float4 se4[128 * 16];
  __shared__ float red[128];
  int tid = threadIdx.x;
  int gid = blockIdx.x * 128 + tid;
  int b = gid >> 10, n = gid & 1023;
  const float* zp = ze + ((size_t)b << 16) + n;
  float4 v4[16];
#pragma unroll
  for (int d = 0; d < 16; ++d) {
    v4[d].x = zp[(size_t)(4 * d + 0) << 10];
    v4[d].y = zp[(size_t)(4 * d + 1) << 10];
    v4[d].z = zp[(size_t)(4 * d + 2) << 10];
    v4[d].w = zp[(size_t)(4 * d + 3) << 10];
  }
  float best = 1e30f; int bi = 0;
  for (int c = 0; c < 4; ++c) {
    __syncthreads();
    for (int i = tid; i < 2048; i += 128)
      se4[i] = ((const float4*)emb)[(c << 11) + i];
    __syncthreads();
    for (int k = 0; k < 128; ++k) {
      const float4* e = se4 + (k << 4);
      float s = 0.0f;
#pragma unroll
      for (int d = 0; d < 16; ++d) {
        float4 ev = e[d];
        float t0 = v4[d].x - ev.x; s = fmaf(t0, t0, s);
        float t1 = v4[d].y - ev.y; s = fmaf(t1, t1, s);
        float t2 = v4[d].z - ev.z; s = fmaf(t2, t2, s);
        float t3 = v4[d].w - ev.w; s = fmaf(t3, t3, s);
      }
      if (s < best) { best = s; bi = (c << 7) + k; }
    }
  }
  const float4* eb4 = (const float4*)emb + ((size_t)bi << 4);
  float* qp = zq + ((size_t)b << 16) + n;
  float ls = 0.0f;
#pragma unroll
  for (int d = 0; d < 16; ++d) {
    float4 q = eb4[d];
    qp[(size_t)(4 * d + 0) << 10] = q.x;
    qp[(size_t)(4 * d + 1) << 10] = q.y;
    qp[(size_t)(4 * d + 2) << 10] = q.z;
    qp[(size_t)(4 * d + 3) << 10] = q.w;
    float t0 = q.x - v4[d].x; ls = fmaf(t0, t0, ls);
    float t1 = q.y - v4[d].y; ls = fmaf(t1, t1, ls);
    float t2 = q.z - v4[d].z; ls = fmaf(t2, t2, ls);
    float t3 = q.w - v4[d].w; ls = fmaf(t3, t3, ls);
  }
  red[tid] = ls;
  __syncthreads();
  for (int s = 64; s > 0; s >>= 1) {
    if (tid < s) red[tid] += red[tid + s];
    __syncthreads();
  }
  if (tid == 0) partial[blockIdx.x] = red[0];
}

__global__ __launch_bounds__(256) void loss_fin(
    const float* __restrict__ partial, float* __restrict__ out) {
  __shared__ float red[256];
  int t = threadIdx.x;
  red[t] = partial[t];
  __syncthreads();
  for (int s = 128; s > 0; s >>= 1) {
    if (t < s) red[t] += red[t + s];
    __syncthreads();
  }
  if (t == 0) out[0] = red[0] * (2.0f / 2097152.0f);
}

template<int CIN, int G, int ACT>
__global__ __launch_bounds__(256) void convT_t(
    const float* __restrict__ in, const float* __restrict__ wt,
    const float* __restrict__ bias, float* __restrict__ out,
    int Cout, int Hin, int Win) {
  const int Hout = Hin * 2, Wout = Win * 2;
  const int TW = Win >> 4;
  __shared__ float tile[18 * 19];
  int tid = threadIdx.x;
  int txl = tid & 15, tyl = tid >> 4;
  int tyt = blockIdx.x / TW, txt = blockIdx.x - tyt * TW;
  int ty0 = tyt << 4, tx0 = txt << 4;
  int og = blockIdx.y % (Cout / G);
  int b  = blockIdx.y / (Cout / G);
  int o0 = og * G;
  const int iy_org = ty0 - 1, ix_org = tx0 - 1;
  const float* ip = in + (size_t)b * CIN * Hin * Win;
  float a00[G], a01[G], a10[G], a11[G];
#pragma unroll
  for (int j = 0; j < G; ++j) {
    float bb = bias[o0 + j];
    a00[j] = bb; a01[j] = bb; a10[j] = bb; a11[j] = bb;
  }
  const int lb = tyl * 19 + txl;
  for (int i = 0; i < CIN; ++i) {
    const float* ic = ip + (size_t)i * Hin * Win;
    __syncthreads();
#pragma unroll
    for (int k = 0; k < 2; ++k) {
      int idx = tid + k * 256;
      if (idx < 18 * 18) {
        int r = idx / 18, c = idx - r * 18;
        int iy = iy_org + r, ix = ix_org + c;
        float v = ((unsigned)iy < (unsigned)Hin && (unsigned)ix < (unsigned)Win)
                      ? ic[(size_t)iy * Win + ix] : 0.0f;
        tile[r * 19 + c] = v;
      }
    }
    __syncthreads();
    float x00 = tile[lb],          x01 = tile[lb + 1],      x02 = tile[lb + 2];
    float x10 = tile[lb + 19],     x11 = tile[lb + 20],     x12 = tile[lb + 21];
    float x20 = tile[lb + 38],     x21 = tile[lb + 39],     x22 = tile[lb + 40];
    const float* wv = wt + ((size_t)i * Cout + o0) * 16;
#pragma unroll
    for (int j = 0; j < G; ++j) {
      const float* w4 = wv + j * 16;
      a00[j] = fmaf(x11, w4[5],  fmaf(x10, w4[7],  fmaf(x01, w4[13], fmaf(x00, w4[15], a00[j]))));
      a01[j] = fmaf(x12, w4[4],  fmaf(x11, w4[6],  fmaf(x02, w4[12], fmaf(x01, w4[14], a01[j]))));
      a10[j] = fmaf(x21, w4[1],  fmaf(x20, w4[3],  fmaf(x11, w4[9],  fmaf(x10, w4[11], a10[j]))));
      a11[j] = fmaf(x22, w4[0],  fmaf(x21, w4[2],  fmaf(x12, w4[8],  fmaf(x11, w4[10], a11[j]))));
    }
  }
  size_t cs = (size_t)Hout * Wout;
  int ty = ty0 + tyl, tx = tx0 + txl;
  size_t base = ((size_t)(b * Cout + o0) * Hout + 2 * (size_t)ty) * Wout + 2 * tx;
#pragma unroll
  for (int j = 0; j < G; ++j) {
    float v00 = a00[j], v01 = a01[j], v10 = a10[j], v11 = a11[j];
    if (ACT == 1) {
      v00 = fmaxf(v00, 0.0f); v01 = fmaxf(v01, 0.0f);
      v10 = fmaxf(v10, 0.0f); v11 = fmaxf(v11, 0.0f);
    } else if (ACT == 2) {
      v00 = 1.0f / (1.0f + expf(-v00)); v01 = 1.0f / (1.0f + expf(-v01));
      v10 = 1.0f / (1.0f + expf(-v10)); v11 = 1.0f / (1.0f + expf(-v11));
    }
    *(float2*)(out + base + (size_t)j * cs)        = make_float2(v00, v01);
    *(float2*)(out + base + (size_t)j * cs + Wout) = make_float2(v10, v11);
  }
}

extern "C" void kernel_launch(void* const* d_in, const int* in_sizes, int n_in,
                              void* d_out, int out_size, void* d_ws, size_t ws_size,
                              hipStream_t stream) {
  const float* x   = (const float*)d_in[0];
  const float* ew1 = (const float*)d_in[1];
  const float* eb1 = (const float*)d_in[2];
  const float* ew2 = (const float*)d_in[3];
  const float* eb2 = (const float*)d_in[4];
  const float* ew3 = (const float*)d_in[5];
  const float* eb3 = (const float*)d_in[6];
  const float* pw  = (const float*)d_in[7];
  const float* pb  = (const float*)d_in[8];
  const float* emb = (const float*)d_in[9];
  const float* dw1 = (const float*)d_in[10];
  const float* db1 = (const float*)d_in[11];
  const float* dw2 = (const float*)d_in[12];
  const float* db2 = (const float*)d_in[13];
  const float* dw3 = (const float*)d_in[14];
  const float* db3 = (const float*)d_in[15];
  float* out = (float*)d_out;
  char* ws = (char*)d_ws;

  const size_t PER  = 13107200ull;
  const size_t WEXT = 4096ull + 13631488ull;
  int CB = 32;
  while (CB > 1 && (size_t)CB * PER + WEXT > ws_size) CB >>= 1;
  const size_t SA = (size_t)CB * 8388608ull;
  const size_t SB = (size_t)CB * 4194304ull;
  const size_t SC = (size_t)CB * 262144ull;
  float* A    = (float*)(ws);              // h1(packed) -> h3(f32) -> d2(f32)
  float* Bp   = (float*)(ws + SA);         // h2(packed) -> d1(packed)
  float* ze   = (float*)(ws + SA + SB);
  float* zq   = (float*)(ws + SA + SB + SC);
  float* part = (float*)(ws + SA + SB + 2 * SC);           // 256 floats
  _Float16* wh2  = (_Float16*)(ws + SA + SB + 2 * SC + 4096);
  _Float16* wl2  = wh2 + 524288;    // conv2: 256*128*16
  _Float16* wh3  = wl2 + 524288;
  _Float16* wl3  = wh3 + 2097152;   // conv3: 512*256*16
  _Float16* whT1 = wl3 + 2097152;
  _Float16* wlT1 = whT1 + 262144;   // convT1: 64*256*16
  _Float16* whT2 = wlT1 + 262144;
  _Float16* wlT2 = whT2 + 524288;   // convT2: 256*128*16

  wsplit_k<128><<<128, 256, 0, stream>>>(ew2, wh2, wl2, 256);
  wsplit_k<256><<<512, 256, 0, stream>>>(ew3, wh3, wl3, 512);
  wsplitT_k<64><<<64,  256, 0, stream>>>(dw1, whT1, wlT1, 256);
  wsplitT_k<256><<<128, 256, 0, stream>>>(dw2, whT2, wlT2, 128);

  for (int c0 = 0; c0 < 32; c0 += CB) {
    const float* xc = x + (size_t)c0 * 3 * 65536;
    float* outc = out + (size_t)c0 * 3 * 65536;
    // encoder: conv1 f32 -> h1 packed; conv2 MFMA packed->packed;
    // conv3 MFMA packed->f32; 1x1 f32
    conv_t<3, 16, 1, 1><<<dim3(64, CB * 8), 256, 0, stream>>>(xc, ew1, eb1, A, 128, 256, 256);
    conv_mfma2<128, 256, 1, 2, 1, 1><<<dim3(128, CB),    256, 0, stream>>>(
        (const unsigned*)A,  wh2, wl2, eb2, Bp, 128, 128);
    conv_mfma2<256, 512, 2, 2, 1, 0><<<dim3(32, CB * 2), 256, 0, stream>>>(
        (const unsigned*)Bp, wh3, wl3, eb3, A, 64, 64);
    conv1x1_k<512, 4><<<dim3(4, CB * 16), 256, 0, stream>>>(A, pw, pb, ze, 64, 1024);
    // VQ
    vq_k<<<CB * 8, 128, 0, stream>>>(ze, emb, zq, part + (size_t)c0 * 8);
    // decoder: convT1 f32->packed; convT2 packed->f32; convT3 f32
    convT_mfma<64,  1, 0, 1><<<dim3(32,  CB * 4), 256, 0, stream>>>(zq, whT1, wlT1, db1, Bp, 256, 32, 32);
    convT_mfma<256, 1, 1, 0><<<dim3(128, CB * 2), 256, 0, stream>>>(Bp, whT2, wlT2, db2, A, 128, 64, 64);
    convT_t<128, 3, 2><<<dim3(64, CB * 1), 256, 0, stream>>>(A, dw3, db3, outc, 3, 128, 128);
  }
  loss_fin<<<1, 256, 0, stream>>>(part, out + (size_t)(out_size - 1));
}